// Round 12
// baseline (4838.640 us; speedup 1.0000x reference)
//
#include <hip/hip_runtime.h>
#include <hip/hip_bf16.h>

// Problem constants
#define NHEAD 8
#define SLEN 64
#define TLEN 32
#define NNODE 512
#define NEDGE 16384
#define NLAYER 4

typedef __attribute__((ext_vector_type(8))) __bf16 bf16x8;
typedef __attribute__((ext_vector_type(4))) __bf16 bf16x4;
typedef __attribute__((ext_vector_type(4))) float  f32x4;

// ---------------------------------------------------------------------------
// async global->LDS 16B (wave-uniform LDS base + lane*16 semantics)
// ---------------------------------------------------------------------------
__device__ __forceinline__ void gload16(const void* g, void* l)
{
    __builtin_amdgcn_global_load_lds(
        (const __attribute__((address_space(1))) void*)g,
        (__attribute__((address_space(3))) void*)l, 16, 0, 0);
}

// ---------------------------------------------------------------------------
// bf16 GEMM (m97 structure): A[M][K] bf16, Bt[N][K] bf16 (pre-transposed),
// C = A@B + bias [+ Res].  outMode: 0=f32, 1=f32+relu, 2=bf16+relu, 3=bf16.
// Res (nullable, bf16, same ldc): fused residual add (epilogue, fp32).
// BM=128, BN template {128,64}. M%128==0, N%BN==0, K%64==0.
// ---------------------------------------------------------------------------
template<int BN>
__global__ __launch_bounds__(256) void gemm_bf16(
    const __bf16* __restrict__ A, int lda,
    const __bf16* __restrict__ Bt, int ldb,
    const float* __restrict__ bias,
    const __bf16* __restrict__ Res,
    float* __restrict__ Cf, __bf16* __restrict__ Cb, int ldc,
    int M, int N, int K, int outMode)
{
    constexpr int FM = (BN == 128) ? 4 : 2;
    __shared__ __bf16 As[128 * 64];
    __shared__ __bf16 Bs[BN * 64];
    const int tid  = threadIdx.x;
    const int wid  = tid >> 6;
    const int lane = tid & 63;
    const int wr = (BN == 128) ? (wid >> 1) : wid;
    const int wc = (BN == 128) ? (wid & 1) : 0;
    const int m0 = blockIdx.y * 128, n0 = blockIdx.x * BN;

    const int srow = wid * 8 + (lane >> 3);
    const int scol = (lane & 7) * 8;
    const int lr = lane & 15;
    const int kg = (lane >> 4) * 8;

    f32x4 acc[FM][4];
    #pragma unroll
    for (int m = 0; m < FM; ++m)
        #pragma unroll
        for (int n = 0; n < 4; ++n)
            acc[m][n] = (f32x4){0.0f, 0.0f, 0.0f, 0.0f};

    for (int k0 = 0; k0 < K; k0 += 64) {
        #pragma unroll
        for (int g = 0; g < 4; ++g) {
            const __bf16* ga = A + (size_t)(m0 + g * 32 + srow) * lda + k0 + scol;
            gload16(ga, &As[(g * 32 + wid * 8) * 64]);
        }
        #pragma unroll
        for (int g = 0; g < BN / 32; ++g) {
            const __bf16* gb = Bt + (size_t)(n0 + g * 32 + srow) * ldb + k0 + scol;
            gload16(gb, &Bs[(g * 32 + wid * 8) * 64]);
        }
        __syncthreads();
        #pragma unroll
        for (int kk = 0; kk < 64; kk += 32) {
            bf16x8 fa[FM], fb[4];
            #pragma unroll
            for (int m = 0; m < FM; ++m)
                fa[m] = *reinterpret_cast<const bf16x8*>(
                    &As[(wr * (16 * FM) + m * 16 + lr) * 64 + kk + kg]);
            #pragma unroll
            for (int n = 0; n < 4; ++n)
                fb[n] = *reinterpret_cast<const bf16x8*>(
                    &Bs[(wc * 64 + n * 16 + lr) * 64 + kk + kg]);
            #pragma unroll
            for (int m = 0; m < FM; ++m)
                #pragma unroll
                for (int n = 0; n < 4; ++n)
                    acc[m][n] = __builtin_amdgcn_mfma_f32_16x16x32_bf16(
                        fa[m], fb[n], acc[m][n], 0, 0, 0);
        }
        __syncthreads();
    }

    const int cr = (lane >> 4) * 4;
    const int cc = lane & 15;
    #pragma unroll
    for (int n = 0; n < 4; ++n) {
        const int gcol = n0 + wc * 64 + n * 16 + cc;
        const float bb = bias[gcol];
        #pragma unroll
        for (int m = 0; m < FM; ++m) {
            #pragma unroll
            for (int j = 0; j < 4; ++j) {
                const int grow = m0 + wr * (16 * FM) + m * 16 + cr + j;
                float v = acc[m][n][j] + bb;
                if (Res) v += (float)Res[(size_t)grow * ldc + gcol];
                if (outMode == 1 || outMode == 2) v = fmaxf(v, 0.0f);
                if (outMode >= 2) Cb[(size_t)grow * ldc + gcol] = (__bf16)v;
                else              Cf[(size_t)grow * ldc + gcol] = v;
            }
        }
    }
}

// ---------------------------------------------------------------------------
// fp32 GEMM (input projections only)
// ---------------------------------------------------------------------------
__global__ __launch_bounds__(256) void gemm_bias(
    const float* __restrict__ A, int lda,
    const float* __restrict__ B, int ldb,
    const float* __restrict__ bias,
    float* __restrict__ C, int ldc,
    int M, int N, int K, int relu)
{
    __shared__ float As[16][68];
    __shared__ float Bs[16][68];
    const int tid = threadIdx.x;
    const int tx = tid & 15, ty = tid >> 4;
    const int m0 = blockIdx.y * 64, n0 = blockIdx.x * 64;
    const int liA_m = tid >> 2;
    const int liA_k = (tid & 3) * 4;
    const int liB_n = (tid & 15) * 4;
    const int liB_k = tid >> 4;
    float acc[4][4] = {};
    for (int k0 = 0; k0 < K; k0 += 16) {
        float4 av = *reinterpret_cast<const float4*>(&A[(size_t)(m0 + liA_m) * lda + k0 + liA_k]);
        float4 bv = *reinterpret_cast<const float4*>(&B[(size_t)(k0 + liB_k) * ldb + n0 + liB_n]);
        As[liA_k + 0][liA_m] = av.x;
        As[liA_k + 1][liA_m] = av.y;
        As[liA_k + 2][liA_m] = av.z;
        As[liA_k + 3][liA_m] = av.w;
        *reinterpret_cast<float4*>(&Bs[liB_k][liB_n]) = bv;
        __syncthreads();
        #pragma unroll
        for (int kk = 0; kk < 16; ++kk) {
            float4 a4 = *reinterpret_cast<const float4*>(&As[kk][ty * 4]);
            float4 b4 = *reinterpret_cast<const float4*>(&Bs[kk][tx * 4]);
            float a[4] = {a4.x, a4.y, a4.z, a4.w};
            float b[4] = {b4.x, b4.y, b4.z, b4.w};
            #pragma unroll
            for (int i = 0; i < 4; ++i)
                #pragma unroll
                for (int j = 0; j < 4; ++j)
                    acc[i][j] += a[i] * b[j];
        }
        __syncthreads();
    }
    #pragma unroll
    for (int i = 0; i < 4; ++i) {
        const int m = m0 + ty * 4 + i;
        #pragma unroll
        for (int j = 0; j < 4; ++j) {
            const int n = n0 + tx * 4 + j;
            float v = acc[i][j] + bias[n];
            if (relu) v = fmaxf(v, 0.0f);
            C[(size_t)m * ldc + n] = v;
        }
    }
}

// ---------------------------------------------------------------------------
// Tiled transpose + fp32->bf16: in [L][K][N] -> out [L][N][K] (L = gridDim.z)
// ---------------------------------------------------------------------------
__global__ __launch_bounds__(256) void transpose_w(
    const float* __restrict__ in, __bf16* __restrict__ out, int K, int N)
{
    __shared__ __bf16 t[32][33];
    const int l = blockIdx.z;
    in  += (size_t)l * K * N;
    out += (size_t)l * K * N;
    const int k0 = blockIdx.y * 32, n0 = blockIdx.x * 32;
    const int tx = threadIdx.x & 31, ty = threadIdx.x >> 5;
    #pragma unroll
    for (int i = 0; i < 32; i += 8)
        t[ty + i][tx] = (__bf16)in[(size_t)(k0 + ty + i) * N + n0 + tx];
    __syncthreads();
    #pragma unroll
    for (int i = 0; i < 32; i += 8)
        out[(size_t)(n0 + ty + i) * K + k0 + tx] = t[tx][ty + i];
}

// ---------------------------------------------------------------------------
__global__ __launch_bounds__(256) void conv_bf16(
    const float* __restrict__ in, __bf16* __restrict__ out, int total4)
{
    const int i = blockIdx.x * 256 + threadIdx.x;
    if (i >= total4) return;
    const float4 v = *reinterpret_cast<const float4*>(&in[(size_t)i * 4]);
    bf16x4 w;
    w[0] = (__bf16)v.x; w[1] = (__bf16)v.y; w[2] = (__bf16)v.z; w[3] = (__bf16)v.w;
    *reinterpret_cast<bf16x4*>(&out[(size_t)i * 4]) = w;
}

// ---------------------------------------------------------------------------
__global__ __launch_bounds__(256) void permute_in(
    const float* __restrict__ in, float* __restrict__ out, int L, int CH, int total)
{
    const int idx = blockIdx.x * 256 + threadIdx.x;
    if (idx >= total) return;
    const int c = idx % CH;
    const int r = idx / CH;       // r = l*512 + n
    const int n = r & 511;
    const int l = r >> 9;
    out[((size_t)n * L + l) * CH + c] = in[idx];
}

// ---------------------------------------------------------------------------
// Permute F bf16 (16384 x 64): node-major row n*32+t -> t-major row t*512+n
// ---------------------------------------------------------------------------
__global__ __launch_bounds__(256) void permute_F(
    const __bf16* __restrict__ in, __bf16* __restrict__ out)
{
    const int idx = blockIdx.x * 256 + threadIdx.x;   // 16384*64 total
    if (idx >= 16384 * 64) return;
    const int c = idx & 63;
    const int r = idx >> 6;
    const int n = r >> 5;
    const int t = r & 31;
    out[((size_t)(t * 512 + n)) * 64 + c] = in[idx];
}

// ---------------------------------------------------------------------------
// MFMA attention: one wave per (node, head). Q/K fragments loaded directly
// from global; only V-transpose + P in LDS.
// ---------------------------------------------------------------------------
template<int LQ, int LK, bool CAUSAL>
__global__ __launch_bounds__(64) void attn_mfma(
    const __bf16* __restrict__ Q, int ldq,
    const __bf16* __restrict__ Kp, int ldk,
    const __bf16* __restrict__ Vp, int ldv,
    __bf16* __restrict__ O, int ldo)
{
    constexpr int QF = LQ / 16, KF = LK / 16;
    constexpr int PSTR = LK + 8;
    __shared__ __bf16 Vt[64 * PSTR];
    __shared__ __bf16 Ps[LQ * PSTR];
    const int n = blockIdx.x >> 3;
    const int h = blockIdx.x & 7;
    const int lane = threadIdx.x;
    const int lr = lane & 15;
    const int g4 = lane >> 4;
    const int kg = g4 * 8;

    if (lane < LK) {
        #pragma unroll
        for (int j = 0; j < 8; ++j) {
            bf16x8 vv = *reinterpret_cast<const bf16x8*>(
                &Vp[(size_t)(n * LK + lane) * ldv + h * 64 + j * 8]);
            #pragma unroll
            for (int e = 0; e < 8; ++e)
                Vt[(j * 8 + e) * PSTR + lane] = vv[e];
        }
    }

    f32x4 s[QF][KF];
    #pragma unroll
    for (int qi = 0; qi < QF; ++qi)
        #pragma unroll
        for (int ki = 0; ki < KF; ++ki)
            s[qi][ki] = (f32x4){0.0f, 0.0f, 0.0f, 0.0f};
    #pragma unroll
    for (int kk = 0; kk < 64; kk += 32) {
        bf16x8 fa[QF], fb[KF];
        #pragma unroll
        for (int qi = 0; qi < QF; ++qi)
            fa[qi] = *reinterpret_cast<const bf16x8*>(
                &Q[(size_t)(n * LQ + qi * 16 + lr) * ldq + h * 64 + kk + kg]);
        #pragma unroll
        for (int ki = 0; ki < KF; ++ki)
            fb[ki] = *reinterpret_cast<const bf16x8*>(
                &Kp[(size_t)(n * LK + ki * 16 + lr) * ldk + h * 64 + kk + kg]);
        #pragma unroll
        for (int qi = 0; qi < QF; ++qi)
            #pragma unroll
            for (int ki = 0; ki < KF; ++ki)
                s[qi][ki] = __builtin_amdgcn_mfma_f32_16x16x32_bf16(fa[qi], fb[ki], s[qi][ki], 0, 0, 0);
    }

    float inv_s[QF][4];
    #pragma unroll
    for (int qi = 0; qi < QF; ++qi) {
        #pragma unroll
        for (int j = 0; j < 4; ++j) {
            const int row = qi * 16 + g4 * 4 + j;
            float mx = -1e30f;
            #pragma unroll
            for (int ki = 0; ki < KF; ++ki) {
                float v = s[qi][ki][j] * 0.125f;
                if (CAUSAL) { const int col = ki * 16 + lr; if (col > row) v = -1e30f; }
                s[qi][ki][j] = v;
                mx = fmaxf(mx, v);
            }
            #pragma unroll
            for (int d = 1; d < 16; d <<= 1) mx = fmaxf(mx, __shfl_xor(mx, d));
            float sum = 0.0f;
            #pragma unroll
            for (int ki = 0; ki < KF; ++ki) {
                const float p = __expf(s[qi][ki][j] - mx);
                s[qi][ki][j] = p;
                sum += p;
            }
            #pragma unroll
            for (int d = 1; d < 16; d <<= 1) sum += __shfl_xor(sum, d);
            inv_s[qi][j] = 1.0f / sum;
            #pragma unroll
            for (int ki = 0; ki < KF; ++ki)
                Ps[row * PSTR + ki * 16 + lr] = (__bf16)s[qi][ki][j];
        }
    }
    __syncthreads();

    f32x4 o[QF][4];
    #pragma unroll
    for (int qi = 0; qi < QF; ++qi)
        #pragma unroll
        for (int di = 0; di < 4; ++di)
            o[qi][di] = (f32x4){0.0f, 0.0f, 0.0f, 0.0f};
    #pragma unroll
    for (int kk = 0; kk < LK; kk += 32) {
        bf16x8 fa[QF], fb[4];
        #pragma unroll
        for (int qi = 0; qi < QF; ++qi)
            fa[qi] = *reinterpret_cast<const bf16x8*>(&Ps[(qi * 16 + lr) * PSTR + kk + kg]);
        #pragma unroll
        for (int di = 0; di < 4; ++di)
            fb[di] = *reinterpret_cast<const bf16x8*>(&Vt[(di * 16 + lr) * PSTR + kk + kg]);
        #pragma unroll
        for (int qi = 0; qi < QF; ++qi)
            #pragma unroll
            for (int di = 0; di < 4; ++di)
                o[qi][di] = __builtin_amdgcn_mfma_f32_16x16x32_bf16(fa[qi], fb[di], o[qi][di], 0, 0, 0);
    }
    #pragma unroll
    for (int qi = 0; qi < QF; ++qi)
        #pragma unroll
        for (int di = 0; di < 4; ++di)
            #pragma unroll
            for (int j = 0; j < 4; ++j) {
                const int row = qi * 16 + g4 * 4 + j;
                O[(size_t)(n * LQ + row) * ldo + h * 64 + di * 16 + lr] =
                    (__bf16)(o[qi][di][j] * inv_s[qi][j]);
            }
}

// ---------------------------------------------------------------------------
// LayerNorm(512) bf16, vectorized (lane owns 8 contiguous channels).
// ---------------------------------------------------------------------------
template<bool HASR, bool F32OUT>
__global__ __launch_bounds__(256) void ln_bf16(
    const __bf16* __restrict__ X, const __bf16* __restrict__ Rb,
    const float* __restrict__ g, const float* __restrict__ b,
    __bf16* __restrict__ outb, float* __restrict__ outf, int ntok)
{
    const int wid = threadIdx.x >> 6, lane = threadIdx.x & 63;
    const int row = blockIdx.x * 4 + wid;
    if (row >= ntok) return;
    const size_t base = (size_t)row * 512;
    const int c0 = lane * 8;
    const bf16x8 xv = *reinterpret_cast<const bf16x8*>(&X[base + c0]);
    float v[8];
    float s = 0.0f;
    if (HASR) {
        const bf16x8 rv = *reinterpret_cast<const bf16x8*>(&Rb[base + c0]);
        #pragma unroll
        for (int j = 0; j < 8; ++j) { v[j] = (float)xv[j] + (float)rv[j]; s += v[j]; }
    } else {
        #pragma unroll
        for (int j = 0; j < 8; ++j) { v[j] = (float)xv[j]; s += v[j]; }
    }
    #pragma unroll
    for (int d = 32; d >= 1; d >>= 1) s += __shfl_xor(s, d, 64);
    const float mean = s * (1.0f / 512.0f);
    float vs = 0.0f;
    #pragma unroll
    for (int j = 0; j < 8; ++j) { const float d = v[j] - mean; vs += d * d; }
    #pragma unroll
    for (int d = 32; d >= 1; d >>= 1) vs += __shfl_xor(vs, d, 64);
    const float rstd = rsqrtf(vs * (1.0f / 512.0f) + 1e-5f);
    const float4 g0 = *reinterpret_cast<const float4*>(&g[c0]);
    const float4 g1 = *reinterpret_cast<const float4*>(&g[c0 + 4]);
    const float4 b0 = *reinterpret_cast<const float4*>(&b[c0]);
    const float4 b1 = *reinterpret_cast<const float4*>(&b[c0 + 4]);
    const float gg[8] = {g0.x, g0.y, g0.z, g0.w, g1.x, g1.y, g1.z, g1.w};
    const float bb[8] = {b0.x, b0.y, b0.z, b0.w, b1.x, b1.y, b1.z, b1.w};
    if (F32OUT) {
        f32x4 o0, o1;
        #pragma unroll
        for (int j = 0; j < 4; ++j) o0[j] = (v[j] - mean) * rstd * gg[j] + bb[j];
        #pragma unroll
        for (int j = 0; j < 4; ++j) o1[j] = (v[4 + j] - mean) * rstd * gg[4 + j] + bb[4 + j];
        *reinterpret_cast<f32x4*>(&outf[base + c0]) = o0;
        *reinterpret_cast<f32x4*>(&outf[base + c0 + 4]) = o1;
    } else {
        bf16x8 w;
        #pragma unroll
        for (int j = 0; j < 8; ++j) w[j] = (__bf16)((v[j] - mean) * rstd * gg[j] + bb[j]);
        *reinterpret_cast<bf16x8*>(&outb[base + c0]) = w;
    }
}

// ---------------------------------------------------------------------------
__global__ __launch_bounds__(256) void add_posenc(float* __restrict__ x, int L, int total)
{
    const int idx = blockIdx.x * 256 + threadIdx.x;
    if (idx >= total) return;
    const int d = idx & 511;
    const int row = idx >> 9;
    const int l = row % L;
    const int i2 = d & ~1;
    const float freq = expf(-9.210340371976184f * (float)i2 / 512.0f);
    const float a = (float)l * freq;
    x[idx] += (d & 1) ? cosf(a) : sinf(a);
}

// ---------------------------------------------------------------------------
__global__ void zero_ints(int* __restrict__ p, int n)
{
    const int i = blockIdx.x * 256 + threadIdx.x;
    if (i < n) p[i] = 0;
}

__global__ void count_deg(const int* __restrict__ edst, int* __restrict__ deg)
{
    const int e = blockIdx.x * 256 + threadIdx.x;
    if (e < NEDGE) atomicAdd(&deg[edst[e]], 1);
}

__global__ void scan512(const int* __restrict__ deg, int* __restrict__ off)
{
    __shared__ int s[512];
    const int tid = threadIdx.x;
    s[tid] = deg[tid];
    __syncthreads();
    for (int d = 1; d < 512; d <<= 1) {
        const int t = (tid >= d) ? s[tid - d] : 0;
        __syncthreads();
        s[tid] += t;
        __syncthreads();
    }
    off[tid + 1] = s[tid];
    if (tid == 0) off[0] = 0;
}

__global__ void fill_eid(const int* __restrict__ edst, const int* __restrict__ off,
                         int* __restrict__ cur, int* __restrict__ eid)
{
    const int e = blockIdx.x * 256 + threadIdx.x;
    if (e < NEDGE) {
        const int d = edst[e];
        const int pos = off[d] + atomicAdd(&cur[d], 1);
        eid[pos] = e;
    }
}

// ---------------------------------------------------------------------------
// GATv2 (online softmax, t-major tensors: row = t*512 + node).
// FINAL: fp32 to d_out; else bf16 out (feeds g2 bf16 GEMM).
// ---------------------------------------------------------------------------
template<bool FINAL>
__global__ __launch_bounds__(256) void gatv2_kernel(
    const float* __restrict__ xl, const float* __restrict__ xr,
    const float* __restrict__ att, const float* __restrict__ bias,
    const int* __restrict__ off, const int* __restrict__ eid,
    const int* __restrict__ esrc,
    __bf16* __restrict__ outb16, float* __restrict__ outd)
{
    const int blk = blockIdx.x;       // t*NNODE + i  (== t-major row)
    const int i = blk & (NNODE - 1);
    const int t = blk >> 9;
    const int tid = threadIdx.x;
    const float xrv = xr[(size_t)blk * 256 + tid];
    const float av = att[tid];
    const int e0 = off[i], e1 = off[i + 1];
    float m = -1e30f, den = 0.0f, acc = 0.0f;
    for (int idx = e0; idx < e1; ++idx) {
        const int e = eid[idx];
        const int s = esrc[e];
        const float xlv = xl[((size_t)(t * 512 + s)) * 256 + tid];
        float z = xlv + xrv;
        z = (z > 0.0f) ? z : 0.2f * z;
        float w = z * av;
        #pragma unroll
        for (int d = 16; d >= 1; d >>= 1) w += __shfl_xor(w, d, 32);
        const float mn = fmaxf(m, w);
        const float sc = __expf(m - mn);
        const float p  = __expf(w - mn);
        den = den * sc + p;
        acc = acc * sc + p * xlv;
        m = mn;
    }
    float o = (den > 0.0f) ? acc / den : 0.0f;
    o += bias[tid];
    if (FINAL) {
        o = fmaxf(o, 0.0f);
        outd[(size_t)blk * 256 + tid] = o;
    } else {
        outb16[(size_t)blk * 256 + tid] = (__bf16)o;   // t-major, bf16
    }
}

// ---------------------------------------------------------------------------
extern "C" void kernel_launch(void* const* d_in, const int* in_sizes, int n_in,
                              void* d_out, int out_size, void* d_ws, size_t ws_size,
                              hipStream_t stream)
{
    const float* src       = (const float*)d_in[0];
    const float* tgt       = (const float*)d_in[1];
    const float* w_enc_in  = (const float*)d_in[2];
    const float* b_enc_in  = (const float*)d_in[3];
    const float* w_dec_in  = (const float*)d_in[4];
    const float* b_dec_in  = (const float*)d_in[5];
    const float* w_map     = (const float*)d_in[6];
    const float* b_map     = (const float*)d_in[7];
    const float* enc_qkv_w = (const float*)d_in[8];
    const float* enc_qkv_b = (const float*)d_in[9];
    const float* enc_out_w = (const float*)d_in[10];
    const float* enc_out_b = (const float*)d_in[11];
    const float* enc_ff1_w = (const float*)d_in[12];
    const float* enc_ff1_b = (const float*)d_in[13];
    const float* enc_ff2_w = (const float*)d_in[14];
    const float* enc_ff2_b = (const float*)d_in[15];
    const float* enc_ln1_g = (const float*)d_in[16];
    const float* enc_ln1_b = (const float*)d_in[17];
    const float* enc_ln2_g = (const float*)d_in[18];
    const float* enc_ln2_b = (const float*)d_in[19];
    const float* enc_fn_g  = (const float*)d_in[20];
    const float* enc_fn_b  = (const float*)d_in[21];
    const float* dec_sa_qkv_w = (const float*)d_in[22];
    const float* dec_sa_qkv_b = (const float*)d_in[23];
    const float* dec_sa_out_w = (const float*)d_in[24];
    const float* dec_sa_out_b = (const float*)d_in[25];
    const float* dec_ca_qkv_w = (const float*)d_in[26];
    const float* dec_ca_qkv_b = (const float*)d_in[27];
    const float* dec_ca_out_w = (const float*)d_in[28];
    const float* dec_ca_out_b = (const float*)d_in[29];
    const float* dec_ff1_w = (const float*)d_in[30];
    const float* dec_ff1_b = (const float*)d_in[31];
    const float* dec_ff2_w = (const float*)d_in[32];
    const float* dec_ff2_b = (const float*)d_in[33];
    const float* dec_ln1_g = (const float*)d_in[34];
    const float* dec_ln1_b = (const float*)d_in[35];
    const float* dec_ln2_g = (const float*)d_in[36];
    const float* dec_ln2_b = (const float*)d_in[37];
    const float* dec_ln3_g = (const float*)d_in[38];
    const float* dec_ln3_b = (const float*)d_in[39];
    const float* dec_fn_g  = (const float*)d_in[40];
    const float* dec_fn_b  = (const float*)d_in[41];
    const float* g1_wl   = (const float*)d_in[42];
    const float* g1_wr   = (const float*)d_in[43];
    const float* g1_bl   = (const float*)d_in[44];
    const float* g1_br   = (const float*)d_in[45];
    const float* g1_att  = (const float*)d_in[46];
    const float* g1_bias = (const float*)d_in[47];
    const float* g2_wl   = (const float*)d_in[48];
    const float* g2_wr   = (const float*)d_in[49];
    const float* g2_bl   = (const float*)d_in[50];
    const float* g2_br   = (const float*)d_in[51];
    const float* g2_att  = (const float*)d_in[52];
    const float* g2_bias = (const float*)d_in[53];
    const int*   edge_index = (const int*)d_in[54];
    const int* esrc = edge_index;
    const int* edst = edge_index + NEDGE;

    // ---- layout (floats; total ~149 MiB) ----
    float* wsf = (float*)d_ws;
    __bf16* Xb = (__bf16*)wsf;                          // 32768x512 bf16
    __bf16* Yb = (__bf16*)(wsf + 8388608);              // 16384x512 bf16
    float*  Rf = wsf + 12582912;                        // R: 8,388,608 f (32MB)
    float*  Mf = wsf + 20971520;                        // M: 8,388,608 f (32MB)
    float*  Wf = wsf + 29360128;                        // W: 8,388,608 f (32MB)
    float*  F  = wsf + 37748736;                        // 1,048,576 f (4MB)
    int* ipool = (int*)(wsf + 38797312);
    int* deg = ipool;
    int* off = deg + 512;
    int* cur = off + 516;
    int* eid = cur + 512;
    __bf16* Rb16 = (__bf16*)Rf;
    __bf16* Mb16 = (__bf16*)Mf;
    __bf16* Wb   = (__bf16*)Wf;
    __bf16* midb = (__bf16*)Rf;          // FFN mid: 16384x2048 bf16 = R+M (64MB)

    auto gemm = [&](const float* A, int lda, const float* B, int ldb, const float* bias,
                    float* Cc, int ldc, int M, int N, int K, int relu) {
        dim3 grid((unsigned)(N / 64), (unsigned)(M / 64));
        gemm_bias<<<grid, 256, 0, stream>>>(A, lda, B, ldb, bias, Cc, ldc, M, N, K, relu);
    };
    auto gemmT = [&](const __bf16* A, int lda, const __bf16* Bt, int ldb,
                     const float* bias, const __bf16* Res, float* Cf, __bf16* Cb, int ldc,
                     int M, int N, int K, int mode) {
        dim3 grid((unsigned)(N / 128), (unsigned)(M / 128));
        gemm_bf16<128><<<grid, 256, 0, stream>>>(A, lda, Bt, ldb, bias, Res, Cf, Cb, ldc, M, N, K, mode);
    };
    auto gemmT64 = [&](const __bf16* A, int lda, const __bf16* Bt, int ldb,
                       const float* bias, const __bf16* Res, float* Cf, __bf16* Cb, int ldc,
                       int M, int N, int K, int mode) {
        dim3 grid((unsigned)(N / 64), (unsigned)(M / 128));
        gemm_bf16<64><<<grid, 256, 0, stream>>>(A, lda, Bt, ldb, bias, Res, Cf, Cb, ldc, M, N, K, mode);
    };
    auto tw = [&](const float* w, __bf16* o, int K, int N, int L) {
        dim3 g((unsigned)(N / 32), (unsigned)(K / 32), (unsigned)L);
        transpose_w<<<g, 256, 0, stream>>>(w, o, K, N);
    };

    // ---- CSR build ----
    zero_ints<<<8, 256, 0, stream>>>(ipool, 512 + 516 + 512);
    count_deg<<<NEDGE / 256, 256, 0, stream>>>(edst, deg);
    scan512<<<1, 512, 0, stream>>>(deg, off);
    fill_eid<<<NEDGE / 256, 256, 0, stream>>>(edst, off, cur, eid);

    // ---- input permute + fp32 projections + posenc + convert to bf16 ----
    {
        float* src_nm = Wf;
        float* Xtmp = Rf;                       // spans R+M
        permute_in<<<4096, 256, 0, stream>>>(src, src_nm, SLEN, 32, 32768 * 32);
        gemm(src_nm, 32, w_enc_in, 512, b_enc_in, Xtmp, 512, 32768, 512, 32, 0);
        add_posenc<<<(32768 * 512) / 256, 256, 0, stream>>>(Xtmp, SLEN, 32768 * 512);
        conv_bf16<<<16384, 256, 0, stream>>>(Xtmp, Xb, 32768 * 128);
        float* tgt_nm = Wf;
        float* Ytmp = Rf;
        permute_in<<<4096, 256, 0, stream>>>(tgt, tgt_nm, TLEN, 64, 16384 * 64);
        gemm(tgt_nm, 64, w_dec_in, 512, b_dec_in, Ytmp, 512, 16384, 512, 64, 0);
        add_posenc<<<(16384 * 512) / 256, 256, 0, stream>>>(Ytmp, TLEN, 16384 * 512);
        conv_bf16<<<8192, 256, 0, stream>>>(Ytmp, Yb, 16384 * 128);
    }

    // ---- encoder weights -> W (bf16, transposed) ----
    __bf16* WeQkv = Wb + 0;
    __bf16* WeOut = Wb + 3145728;
    __bf16* WeFf1 = Wb + 4194304;
    __bf16* WeFf2 = Wb + 8388608;
    tw(enc_qkv_w, WeQkv, 512, 1536, NLAYER);
    tw(enc_out_w, WeOut, 512, 512, NLAYER);
    tw(enc_ff1_w, WeFf1, 512, 2048, NLAYER);
    tw(enc_ff2_w, WeFf2, 2048, 512, NLAYER);

    // ================= encoder (full batch, 32768 rows) =================
    for (int i = 0; i < NLAYER; ++i) {
        // QKV + attention, 4 chunks of 8192 rows (QKV in R, O in M)
        for (int c = 0; c < 4; ++c) {
            gemmT(Xb + (size_t)c * 8192 * 512, 512, WeQkv + (size_t)i * 786432, 512,
                  enc_qkv_b + (size_t)i * 1536, nullptr, nullptr, Rb16, 1536, 8192, 1536, 512, 3);
            attn_mfma<64, 64, false><<<1024, 64, 0, stream>>>(
                Rb16, 1536, Rb16 + 512, 1536, Rb16 + 1024, 1536,
                Mb16 + (size_t)c * 8192 * 512, 512);
        }
        // out-proj + residual fused -> Xb; then in-place LN
        gemmT(Mb16, 512, WeOut + (size_t)i * 262144, 512, enc_out_b + (size_t)i * 512,
              Xb, nullptr, Xb, 512, 32768, 512, 512, 3);
        ln_bf16<false, false><<<8192, 256, 0, stream>>>(Xb, nullptr,
            enc_ln1_g + (size_t)i * 512, enc_ln1_b + (size_t)i * 512, Xb, nullptr, 32768);
        // FFN, 2 chunks of 16384 rows (mid bf16 16384x2048 = R+M)
        for (int s = 0; s < 2; ++s) {
            gemmT(Xb + (size_t)s * 16384 * 512, 512, WeFf1 + (size_t)i * 1048576, 512,
                  enc_ff1_b + (size_t)i * 2048, nullptr, nullptr, midb, 2048, 16384, 2048, 512, 2);
            gemmT64(midb, 2048, WeFf2 + (size_t)i * 1048576, 2048,
                    enc_ff2_b + (size_t)i * 512, Xb + (size_t)s * 16384 * 512,
                    nullptr, Xb + (size_t)s * 16384 * 512, 512, 16384, 512, 2048, 3);
        }
        ln_bf16<false, false><<<8192, 256, 0, stream>>>(Xb, nullptr,
            enc_ln2_g + (size_t)i * 512, enc_ln2_b + (size_t)i * 512, Xb, nullptr, 32768);
    }
    ln_bf16<false, false><<<8192, 256, 0, stream>>>(Xb, nullptr, enc_fn_g, enc_fn_b,
                                                    Xb, nullptr, 32768);
    // Xb is now MEMb

    // ---- decoder weights -> W ----
    __bf16* WdSaQkv = Wb + 0;
    __bf16* WdSaOut = Wb + 3145728;
    __bf16* WdCaQkv = Wb + 4194304;
    __bf16* WdCaOut = Wb + 7340032;
    __bf16* WdFf1   = Wb + 8388608;
    __bf16* WdFf2   = Wb + 12582912;
    tw(dec_sa_qkv_w, WdSaQkv, 512, 1536, NLAYER);
    tw(dec_sa_out_w, WdSaOut, 512, 512, NLAYER);
    tw(dec_ca_qkv_w, WdCaQkv, 512, 1536, NLAYER);
    tw(dec_ca_out_w, WdCaOut, 512, 512, NLAYER);
    tw(dec_ff1_w,    WdFf1,   512, 2048, NLAYER);
    tw(dec_ff2_w,    WdFf2,   2048, 512, NLAYER);

    // ================= decoder (full batch, 16384 rows) =================
    __bf16* ObD  = Mb16;                              // 16384x512 bf16 (16MB)
    __bf16* QbC  = Mb16;                              // 16384x512 bf16 (16MB)
    __bf16* ObCA = (__bf16*)(Mf + 4194304);           // 16384x512 bf16 (16..32MB)
    for (int i = 0; i < NLAYER; ++i) {
        // causal self-attention, 2 chunks of 8192 rows
        for (int c = 0; c < 2; ++c) {
            gemmT(Yb + (size_t)c * 8192 * 512, 512, WdSaQkv + (size_t)i * 786432, 512,
                  dec_sa_qkv_b + (size_t)i * 1536, nullptr, nullptr, Rb16, 1536, 8192, 1536, 512, 3);
            attn_mfma<32, 32, true><<<2048, 64, 0, stream>>>(
                Rb16, 1536, Rb16 + 512, 1536, Rb16 + 1024, 1536,
                ObD + (size_t)c * 8192 * 512, 512);
        }
        gemmT64(ObD, 512, WdSaOut + (size_t)i * 262144, 512, dec_sa_out_b + (size_t)i * 512,
                Yb, nullptr, Yb, 512, 16384, 512, 512, 3);
        ln_bf16<false, false><<<4096, 256, 0, stream>>>(Yb, nullptr,
            dec_ln1_g + (size_t)i * 512, dec_ln1_b + (size_t)i * 512, Yb, nullptr, 16384);
        // cross-attention: Q full (16384), KV 2 chunks of 16384 enc rows
        gemmT64(Yb, 512, WdCaQkv + (size_t)i * 786432, 512,
                dec_ca_qkv_b + (size_t)i * 1536, nullptr, nullptr, QbC, 512, 16384, 512, 512, 3);
        for (int c = 0; c < 2; ++c) {
            gemmT(Xb + (size_t)c * 16384 * 512, 512, WdCaQkv + (size_t)i * 786432 + 262144, 512,
                  dec_ca_qkv_b + (size_t)i * 1536 + 512, nullptr, nullptr, Rb16, 1024, 16384, 1024, 512, 3);
            attn_mfma<32, 64, false><<<2048, 64, 0, stream>>>(
                QbC + (size_t)c * 8192 * 512, 512, Rb16, 1024, Rb16 + 512, 1024,
                ObCA + (size_t)c * 8192 * 512, 512);
        }
        gemmT64(ObCA, 512, WdCaOut + (size_t)i * 262144, 512, dec_ca_out_b + (size_t)i * 512,
                Yb, nullptr, Yb, 512, 16384, 512, 512, 3);
        ln_bf16<false, false><<<4096, 256, 0, stream>>>(Yb, nullptr,
            dec_ln2_g + (size_t)i * 512, dec_ln2_b + (size_t)i * 512, Yb, nullptr, 16384);
        // FFN single chunk (mid = R+M)
        gemmT(Yb, 512, WdFf1 + (size_t)i * 1048576, 512,
              dec_ff1_b + (size_t)i * 2048, nullptr, nullptr, midb, 2048, 16384, 2048, 512, 2);
        gemmT64(midb, 2048, WdFf2 + (size_t)i * 1048576, 2048,
                dec_ff2_b + (size_t)i * 512, Yb, nullptr, Yb, 512, 16384, 512, 2048, 3);
        ln_bf16<false, false><<<4096, 256, 0, stream>>>(Yb, nullptr,
            dec_ln3_g + (size_t)i * 512, dec_ln3_b + (size_t)i * 512, Yb, nullptr, 16384);
    }
    // final decoder LN (in place, bf16)
    ln_bf16<false, false><<<4096, 256, 0, stream>>>(Yb, nullptr, dec_fn_g, dec_fn_b,
                                                    Yb, nullptr, 16384);

    // ---- tail weights (W dead after decoder) ----
    __bf16* Wmapt = Wb;                     // 64x512
    __bf16* G1wlT = Wb + 32768;             // 256x64
    __bf16* G1wrT = Wb + 49152;             // 256x64
    __bf16* G2wlT = Wb + 65536;             // 256x256
    __bf16* G2wrT = Wb + 131072;            // 256x256
    __bf16* Ftb   = Wb + 196608;            // 16384x64 (t-major)
    __bf16* Ibb   = Wb + 1245184;           // 16384x256 (t-major, gat1 out)
    tw(w_map, Wmapt, 512, 64, 1);
    tw(g1_wl, G1wlT, 64, 256, 1);
    tw(g1_wr, G1wrT, 64, 256, 1);
    tw(g2_wl, G2wlT, 256, 256, 1);
    tw(g2_wr, G2wrT, 256, 256, 1);

    // map to FEAT=64 (bf16), permute to t-major
    __bf16* Fb16 = (__bf16*)F;
    gemmT64(Yb, 512, Wmapt, 512, b_map, nullptr, nullptr, Fb16, 64, 16384, 64, 512, 3);
    permute_F<<<4096, 256, 0, stream>>>(Fb16, Ftb);

    // ================= spatial GATv2 (bf16 GEMMs, t-major) =================
    float* G  = Mf;                          // 4,194,304 f
    float* Hb = Mf + 4194304;                // 4,194,304 f
    gemmT64(Ftb, 64, G1wlT, 64, g1_bl, nullptr, G,  nullptr, 256, 16384, 256, 64, 0);
    gemmT64(Ftb, 64, G1wrT, 64, g1_br, nullptr, Hb, nullptr, 256, 16384, 256, 64, 0);
    gatv2_kernel<false><<<16384, 256, 0, stream>>>(G, Hb, g1_att, g1_bias, off, eid, esrc,
                                                   Ibb, nullptr);
    gemmT64(Ibb, 256, G2wlT, 256, g2_bl, nullptr, G,  nullptr, 256, 16384, 256, 256, 0);
    gemmT64(Ibb, 256, G2wrT, 256, g2_br, nullptr, Hb, nullptr, 256, 16384, 256, 256, 0);
    gatv2_kernel<true><<<16384, 256, 0, stream>>>(G, Hb, g2_att, g2_bias, off, eid, esrc,
                                                  nullptr, (float*)d_out);
}

// Round 13
// 4766.206 us; speedup vs baseline: 1.0152x; 1.0152x over previous
//
#include <hip/hip_runtime.h>
#include <hip/hip_bf16.h>

// Problem constants
#define NHEAD 8
#define SLEN 64
#define TLEN 32
#define NNODE 512
#define NEDGE 16384
#define NLAYER 4

typedef __attribute__((ext_vector_type(8))) __bf16 bf16x8;
typedef __attribute__((ext_vector_type(4))) __bf16 bf16x4;
typedef __attribute__((ext_vector_type(4))) float  f32x4;

// ---------------------------------------------------------------------------
// async global->LDS 16B (wave-uniform LDS base + lane*16 semantics)
// ---------------------------------------------------------------------------
__device__ __forceinline__ void gload16(const void* g, void* l)
{
    __builtin_amdgcn_global_load_lds(
        (const __attribute__((address_space(1))) void*)g,
        (__attribute__((address_space(3))) void*)l, 16, 0, 0);
}

// ---------------------------------------------------------------------------
// bf16 GEMM (m97 structure): A[M][K] bf16, Bt[N][K] bf16 (pre-transposed),
// C = A@B + bias [+ Res]. outMode: 0=f32, 1=f32+relu, 2=bf16+relu, 3=bf16.
// BM=128, BN template {128,64}. M%128==0, N%BN==0, K%64==0.
// ---------------------------------------------------------------------------
template<int BN>
__global__ __launch_bounds__(256) void gemm_bf16(
    const __bf16* __restrict__ A, int lda,
    const __bf16* __restrict__ Bt, int ldb,
    const float* __restrict__ bias,
    const __bf16* __restrict__ Res,
    float* __restrict__ Cf, __bf16* __restrict__ Cb, int ldc,
    int M, int N, int K, int outMode)
{
    constexpr int FM = (BN == 128) ? 4 : 2;
    __shared__ __bf16 As[128 * 64];
    __shared__ __bf16 Bs[BN * 64];
    const int tid  = threadIdx.x;
    const int wid  = tid >> 6;
    const int lane = tid & 63;
    const int wr = (BN == 128) ? (wid >> 1) : wid;
    const int wc = (BN == 128) ? (wid & 1) : 0;
    const int m0 = blockIdx.y * 128, n0 = blockIdx.x * BN;

    const int srow = wid * 8 + (lane >> 3);
    const int scol = (lane & 7) * 8;
    const int lr = lane & 15;
    const int kg = (lane >> 4) * 8;

    f32x4 acc[FM][4];
    #pragma unroll
    for (int m = 0; m < FM; ++m)
        #pragma unroll
        for (int n = 0; n < 4; ++n)
            acc[m][n] = (f32x4){0.0f, 0.0f, 0.0f, 0.0f};

    for (int k0 = 0; k0 < K; k0 += 64) {
        #pragma unroll
        for (int g = 0; g < 4; ++g) {
            const __bf16* ga = A + (size_t)(m0 + g * 32 + srow) * lda + k0 + scol;
            gload16(ga, &As[(g * 32 + wid * 8) * 64]);
        }
        #pragma unroll
        for (int g = 0; g < BN / 32; ++g) {
            const __bf16* gb = Bt + (size_t)(n0 + g * 32 + srow) * ldb + k0 + scol;
            gload16(gb, &Bs[(g * 32 + wid * 8) * 64]);
        }
        __syncthreads();
        #pragma unroll
        for (int kk = 0; kk < 64; kk += 32) {
            bf16x8 fa[FM], fb[4];
            #pragma unroll
            for (int m = 0; m < FM; ++m)
                fa[m] = *reinterpret_cast<const bf16x8*>(
                    &As[(wr * (16 * FM) + m * 16 + lr) * 64 + kk + kg]);
            #pragma unroll
            for (int n = 0; n < 4; ++n)
                fb[n] = *reinterpret_cast<const bf16x8*>(
                    &Bs[(wc * 64 + n * 16 + lr) * 64 + kk + kg]);
            #pragma unroll
            for (int m = 0; m < FM; ++m)
                #pragma unroll
                for (int n = 0; n < 4; ++n)
                    acc[m][n] = __builtin_amdgcn_mfma_f32_16x16x32_bf16(
                        fa[m], fb[n], acc[m][n], 0, 0, 0);
        }
        __syncthreads();
    }

    const int cr = (lane >> 4) * 4;
    const int cc = lane & 15;
    #pragma unroll
    for (int n = 0; n < 4; ++n) {
        const int gcol = n0 + wc * 64 + n * 16 + cc;
        const float bb = bias[gcol];
        #pragma unroll
        for (int m = 0; m < FM; ++m) {
            #pragma unroll
            for (int j = 0; j < 4; ++j) {
                const int grow = m0 + wr * (16 * FM) + m * 16 + cr + j;
                float v = acc[m][n][j] + bb;
                if (Res) v += (float)Res[(size_t)grow * ldc + gcol];
                if (outMode == 1 || outMode == 2) v = fmaxf(v, 0.0f);
                if (outMode >= 2) Cb[(size_t)grow * ldc + gcol] = (__bf16)v;
                else              Cf[(size_t)grow * ldc + gcol] = v;
            }
        }
    }
}

// ---------------------------------------------------------------------------
// fp32 GEMM (input projections only)
// ---------------------------------------------------------------------------
__global__ __launch_bounds__(256) void gemm_bias(
    const float* __restrict__ A, int lda,
    const float* __restrict__ B, int ldb,
    const float* __restrict__ bias,
    float* __restrict__ C, int ldc,
    int M, int N, int K, int relu)
{
    __shared__ float As[16][68];
    __shared__ float Bs[16][68];
    const int tid = threadIdx.x;
    const int tx = tid & 15, ty = tid >> 4;
    const int m0 = blockIdx.y * 64, n0 = blockIdx.x * 64;
    const int liA_m = tid >> 2;
    const int liA_k = (tid & 3) * 4;
    const int liB_n = (tid & 15) * 4;
    const int liB_k = tid >> 4;
    float acc[4][4] = {};
    for (int k0 = 0; k0 < K; k0 += 16) {
        float4 av = *reinterpret_cast<const float4*>(&A[(size_t)(m0 + liA_m) * lda + k0 + liA_k]);
        float4 bv = *reinterpret_cast<const float4*>(&B[(size_t)(k0 + liB_k) * ldb + n0 + liB_n]);
        As[liA_k + 0][liA_m] = av.x;
        As[liA_k + 1][liA_m] = av.y;
        As[liA_k + 2][liA_m] = av.z;
        As[liA_k + 3][liA_m] = av.w;
        *reinterpret_cast<float4*>(&Bs[liB_k][liB_n]) = bv;
        __syncthreads();
        #pragma unroll
        for (int kk = 0; kk < 16; ++kk) {
            float4 a4 = *reinterpret_cast<const float4*>(&As[kk][ty * 4]);
            float4 b4 = *reinterpret_cast<const float4*>(&Bs[kk][tx * 4]);
            float a[4] = {a4.x, a4.y, a4.z, a4.w};
            float b[4] = {b4.x, b4.y, b4.z, b4.w};
            #pragma unroll
            for (int i = 0; i < 4; ++i)
                #pragma unroll
                for (int j = 0; j < 4; ++j)
                    acc[i][j] += a[i] * b[j];
        }
        __syncthreads();
    }
    #pragma unroll
    for (int i = 0; i < 4; ++i) {
        const int m = m0 + ty * 4 + i;
        #pragma unroll
        for (int j = 0; j < 4; ++j) {
            const int n = n0 + tx * 4 + j;
            float v = acc[i][j] + bias[n];
            if (relu) v = fmaxf(v, 0.0f);
            C[(size_t)m * ldc + n] = v;
        }
    }
}

// ---------------------------------------------------------------------------
// Tiled transpose + fp32->bf16: in [L][K][N] -> out [L][N][K] (L = gridDim.z)
// ---------------------------------------------------------------------------
__global__ __launch_bounds__(256) void transpose_w(
    const float* __restrict__ in, __bf16* __restrict__ out, int K, int N)
{
    __shared__ __bf16 t[32][33];
    const int l = blockIdx.z;
    in  += (size_t)l * K * N;
    out += (size_t)l * K * N;
    const int k0 = blockIdx.y * 32, n0 = blockIdx.x * 32;
    const int tx = threadIdx.x & 31, ty = threadIdx.x >> 5;
    #pragma unroll
    for (int i = 0; i < 32; i += 8)
        t[ty + i][tx] = (__bf16)in[(size_t)(k0 + ty + i) * N + n0 + tx];
    __syncthreads();
    #pragma unroll
    for (int i = 0; i < 32; i += 8)
        out[(size_t)(n0 + ty + i) * K + k0 + tx] = t[tx][ty + i];
}

// ---------------------------------------------------------------------------
__global__ __launch_bounds__(256) void conv_bf16(
    const float* __restrict__ in, __bf16* __restrict__ out, int total4)
{
    const int i = blockIdx.x * 256 + threadIdx.x;
    if (i >= total4) return;
    const float4 v = *reinterpret_cast<const float4*>(&in[(size_t)i * 4]);
    bf16x4 w;
    w[0] = (__bf16)v.x; w[1] = (__bf16)v.y; w[2] = (__bf16)v.z; w[3] = (__bf16)v.w;
    *reinterpret_cast<bf16x4*>(&out[(size_t)i * 4]) = w;
}

// ---------------------------------------------------------------------------
__global__ __launch_bounds__(256) void permute_in(
    const float* __restrict__ in, float* __restrict__ out, int L, int CH, int total)
{
    const int idx = blockIdx.x * 256 + threadIdx.x;
    if (idx >= total) return;
    const int c = idx % CH;
    const int r = idx / CH;       // r = l*512 + n
    const int n = r & 511;
    const int l = r >> 9;
    out[((size_t)n * L + l) * CH + c] = in[idx];
}

// ---------------------------------------------------------------------------
// Permute F bf16 (16384 x 64): node-major row n*32+t -> t-major row t*512+n
// ---------------------------------------------------------------------------
__global__ __launch_bounds__(256) void permute_F(
    const __bf16* __restrict__ in, __bf16* __restrict__ out)
{
    const int idx = blockIdx.x * 256 + threadIdx.x;   // 16384*64 total
    if (idx >= 16384 * 64) return;
    const int c = idx & 63;
    const int r = idx >> 6;
    const int n = r >> 5;
    const int t = r & 31;
    out[((size_t)(t * 512 + n)) * 64 + c] = in[idx];
}

// ---------------------------------------------------------------------------
// MFMA attention: one wave per (node, head). Q/K fragments loaded directly
// from global; only V-transpose + P in LDS.
// ---------------------------------------------------------------------------
template<int LQ, int LK, bool CAUSAL>
__global__ __launch_bounds__(64) void attn_mfma(
    const __bf16* __restrict__ Q, int ldq,
    const __bf16* __restrict__ Kp, int ldk,
    const __bf16* __restrict__ Vp, int ldv,
    __bf16* __restrict__ O, int ldo)
{
    constexpr int QF = LQ / 16, KF = LK / 16;
    constexpr int PSTR = LK + 8;
    __shared__ __bf16 Vt[64 * PSTR];
    __shared__ __bf16 Ps[LQ * PSTR];
    const int n = blockIdx.x >> 3;
    const int h = blockIdx.x & 7;
    const int lane = threadIdx.x;
    const int lr = lane & 15;
    const int g4 = lane >> 4;
    const int kg = g4 * 8;

    if (lane < LK) {
        #pragma unroll
        for (int j = 0; j < 8; ++j) {
            bf16x8 vv = *reinterpret_cast<const bf16x8*>(
                &Vp[(size_t)(n * LK + lane) * ldv + h * 64 + j * 8]);
            #pragma unroll
            for (int e = 0; e < 8; ++e)
                Vt[(j * 8 + e) * PSTR + lane] = vv[e];
        }
    }

    f32x4 s[QF][KF];
    #pragma unroll
    for (int qi = 0; qi < QF; ++qi)
        #pragma unroll
        for (int ki = 0; ki < KF; ++ki)
            s[qi][ki] = (f32x4){0.0f, 0.0f, 0.0f, 0.0f};
    #pragma unroll
    for (int kk = 0; kk < 64; kk += 32) {
        bf16x8 fa[QF], fb[KF];
        #pragma unroll
        for (int qi = 0; qi < QF; ++qi)
            fa[qi] = *reinterpret_cast<const bf16x8*>(
                &Q[(size_t)(n * LQ + qi * 16 + lr) * ldq + h * 64 + kk + kg]);
        #pragma unroll
        for (int ki = 0; ki < KF; ++ki)
            fb[ki] = *reinterpret_cast<const bf16x8*>(
                &Kp[(size_t)(n * LK + ki * 16 + lr) * ldk + h * 64 + kk + kg]);
        #pragma unroll
        for (int qi = 0; qi < QF; ++qi)
            #pragma unroll
            for (int ki = 0; ki < KF; ++ki)
                s[qi][ki] = __builtin_amdgcn_mfma_f32_16x16x32_bf16(fa[qi], fb[ki], s[qi][ki], 0, 0, 0);
    }

    float inv_s[QF][4];
    #pragma unroll
    for (int qi = 0; qi < QF; ++qi) {
        #pragma unroll
        for (int j = 0; j < 4; ++j) {
            const int row = qi * 16 + g4 * 4 + j;
            float mx = -1e30f;
            #pragma unroll
            for (int ki = 0; ki < KF; ++ki) {
                float v = s[qi][ki][j] * 0.125f;
                if (CAUSAL) { const int col = ki * 16 + lr; if (col > row) v = -1e30f; }
                s[qi][ki][j] = v;
                mx = fmaxf(mx, v);
            }
            #pragma unroll
            for (int d = 1; d < 16; d <<= 1) mx = fmaxf(mx, __shfl_xor(mx, d));
            float sum = 0.0f;
            #pragma unroll
            for (int ki = 0; ki < KF; ++ki) {
                const float p = __expf(s[qi][ki][j] - mx);
                s[qi][ki][j] = p;
                sum += p;
            }
            #pragma unroll
            for (int d = 1; d < 16; d <<= 1) sum += __shfl_xor(sum, d);
            inv_s[qi][j] = 1.0f / sum;
            #pragma unroll
            for (int ki = 0; ki < KF; ++ki)
                Ps[row * PSTR + ki * 16 + lr] = (__bf16)s[qi][ki][j];
        }
    }
    __syncthreads();

    f32x4 o[QF][4];
    #pragma unroll
    for (int qi = 0; qi < QF; ++qi)
        #pragma unroll
        for (int di = 0; di < 4; ++di)
            o[qi][di] = (f32x4){0.0f, 0.0f, 0.0f, 0.0f};
    #pragma unroll
    for (int kk = 0; kk < LK; kk += 32) {
        bf16x8 fa[QF], fb[4];
        #pragma unroll
        for (int qi = 0; qi < QF; ++qi)
            fa[qi] = *reinterpret_cast<const bf16x8*>(&Ps[(qi * 16 + lr) * PSTR + kk + kg]);
        #pragma unroll
        for (int di = 0; di < 4; ++di)
            fb[di] = *reinterpret_cast<const bf16x8*>(&Vt[(di * 16 + lr) * PSTR + kk + kg]);
        #pragma unroll
        for (int qi = 0; qi < QF; ++qi)
            #pragma unroll
            for (int di = 0; di < 4; ++di)
                o[qi][di] = __builtin_amdgcn_mfma_f32_16x16x32_bf16(fa[qi], fb[di], o[qi][di], 0, 0, 0);
    }
    #pragma unroll
    for (int qi = 0; qi < QF; ++qi)
        #pragma unroll
        for (int di = 0; di < 4; ++di)
            #pragma unroll
            for (int j = 0; j < 4; ++j) {
                const int row = qi * 16 + g4 * 4 + j;
                O[(size_t)(n * LQ + row) * ldo + h * 64 + di * 16 + lr] =
                    (__bf16)(o[qi][di][j] * inv_s[qi][j]);
            }
}

// ---------------------------------------------------------------------------
// LayerNorm(512) bf16, vectorized (lane owns 8 contiguous channels).
// ---------------------------------------------------------------------------
template<bool HASR, bool F32OUT>
__global__ __launch_bounds__(256) void ln_bf16(
    const __bf16* __restrict__ X, const __bf16* __restrict__ Rb,
    const float* __restrict__ g, const float* __restrict__ b,
    __bf16* __restrict__ outb, float* __restrict__ outf, int ntok)
{
    const int wid = threadIdx.x >> 6, lane = threadIdx.x & 63;
    const int row = blockIdx.x * 4 + wid;
    if (row >= ntok) return;
    const size_t base = (size_t)row * 512;
    const int c0 = lane * 8;
    const bf16x8 xv = *reinterpret_cast<const bf16x8*>(&X[base + c0]);
    float v[8];
    float s = 0.0f;
    if (HASR) {
        const bf16x8 rv = *reinterpret_cast<const bf16x8*>(&Rb[base + c0]);
        #pragma unroll
        for (int j = 0; j < 8; ++j) { v[j] = (float)xv[j] + (float)rv[j]; s += v[j]; }
    } else {
        #pragma unroll
        for (int j = 0; j < 8; ++j) { v[j] = (float)xv[j]; s += v[j]; }
    }
    #pragma unroll
    for (int d = 32; d >= 1; d >>= 1) s += __shfl_xor(s, d, 64);
    const float mean = s * (1.0f / 512.0f);
    float vs = 0.0f;
    #pragma unroll
    for (int j = 0; j < 8; ++j) { const float d = v[j] - mean; vs += d * d; }
    #pragma unroll
    for (int d = 32; d >= 1; d >>= 1) vs += __shfl_xor(vs, d, 64);
    const float rstd = rsqrtf(vs * (1.0f / 512.0f) + 1e-5f);
    const float4 g0 = *reinterpret_cast<const float4*>(&g[c0]);
    const float4 g1 = *reinterpret_cast<const float4*>(&g[c0 + 4]);
    const float4 b0 = *reinterpret_cast<const float4*>(&b[c0]);
    const float4 b1 = *reinterpret_cast<const float4*>(&b[c0 + 4]);
    const float gg[8] = {g0.x, g0.y, g0.z, g0.w, g1.x, g1.y, g1.z, g1.w};
    const float bb[8] = {b0.x, b0.y, b0.z, b0.w, b1.x, b1.y, b1.z, b1.w};
    if (F32OUT) {
        f32x4 o0, o1;
        #pragma unroll
        for (int j = 0; j < 4; ++j) o0[j] = (v[j] - mean) * rstd * gg[j] + bb[j];
        #pragma unroll
        for (int j = 0; j < 4; ++j) o1[j] = (v[4 + j] - mean) * rstd * gg[4 + j] + bb[4 + j];
        *reinterpret_cast<f32x4*>(&outf[base + c0]) = o0;
        *reinterpret_cast<f32x4*>(&outf[base + c0 + 4]) = o1;
    } else {
        bf16x8 w;
        #pragma unroll
        for (int j = 0; j < 8; ++j) w[j] = (__bf16)((v[j] - mean) * rstd * gg[j] + bb[j]);
        *reinterpret_cast<bf16x8*>(&outb[base + c0]) = w;
    }
}

// ---------------------------------------------------------------------------
__global__ __launch_bounds__(256) void add_posenc(float* __restrict__ x, int L, int total)
{
    const int idx = blockIdx.x * 256 + threadIdx.x;
    if (idx >= total) return;
    const int d = idx & 511;
    const int row = idx >> 9;
    const int l = row % L;
    const int i2 = d & ~1;
    const float freq = expf(-9.210340371976184f * (float)i2 / 512.0f);
    const float a = (float)l * freq;
    x[idx] += (d & 1) ? cosf(a) : sinf(a);
}

// ---------------------------------------------------------------------------
__global__ void zero_ints(int* __restrict__ p, int n)
{
    const int i = blockIdx.x * 256 + threadIdx.x;
    if (i < n) p[i] = 0;
}

__global__ void count_deg(const int* __restrict__ edst, int* __restrict__ deg)
{
    const int e = blockIdx.x * 256 + threadIdx.x;
    if (e < NEDGE) atomicAdd(&deg[edst[e]], 1);
}

__global__ void scan512(const int* __restrict__ deg, int* __restrict__ off)
{
    __shared__ int s[512];
    const int tid = threadIdx.x;
    s[tid] = deg[tid];
    __syncthreads();
    for (int d = 1; d < 512; d <<= 1) {
        const int t = (tid >= d) ? s[tid - d] : 0;
        __syncthreads();
        s[tid] += t;
        __syncthreads();
    }
    off[tid + 1] = s[tid];
    if (tid == 0) off[0] = 0;
}

__global__ void fill_eid(const int* __restrict__ edst, const int* __restrict__ off,
                         int* __restrict__ cur, int* __restrict__ eid)
{
    const int e = blockIdx.x * 256 + threadIdx.x;
    if (e < NEDGE) {
        const int d = edst[e];
        const int pos = off[d] + atomicAdd(&cur[d], 1);
        eid[pos] = e;
    }
}

// ---------------------------------------------------------------------------
// GATv2, register-tiled two-pass (16-edge tiles), t-major tensors.
// Pass1: gather xlv + score into REGISTERS (only fmax on the serial chain).
// Pass2: one exp per edge; one rescale per tile. No extra global traffic.
// FINAL: fp32 to d_out; else bf16 out (feeds g2 bf16 GEMM).
// ---------------------------------------------------------------------------
template<bool FINAL>
__global__ __launch_bounds__(256) void gatv2_kernel(
    const float* __restrict__ xl, const float* __restrict__ xr,
    const float* __restrict__ att, const float* __restrict__ bias,
    const int* __restrict__ off, const int* __restrict__ eid,
    const int* __restrict__ esrc,
    __bf16* __restrict__ outb16, float* __restrict__ outd)
{
    const int blk = blockIdx.x;       // t*NNODE + i  (== t-major row)
    const int i = blk & (NNODE - 1);
    const int t = blk >> 9;
    const int tid = threadIdx.x;
    const float xrv = xr[(size_t)blk * 256 + tid];
    const float av = att[tid];
    const int e0 = off[i], e1 = off[i + 1];
    float m = -1e30f, den = 0.0f, acc = 0.0f;
    for (int base = e0; base < e1; base += 16) {
        float xv[16], ws[16];
        float tm = -1e30f;
        #pragma unroll
        for (int k = 0; k < 16; ++k) {
            const int idx = base + k;           // wave-uniform condition
            float w = -1e30f, xlv = 0.0f;
            if (idx < e1) {
                const int s = esrc[eid[idx]];
                xlv = xl[((size_t)(t * 512 + s)) * 256 + tid];
                float z = xlv + xrv;
                z = (z > 0.0f) ? z : 0.2f * z;  // leaky_relu(0.2)
                w = z * av;
                #pragma unroll
                for (int d = 16; d >= 1; d >>= 1) w += __shfl_xor(w, d, 32);
            }
            ws[k] = w;
            xv[k] = xlv;
            tm = fmaxf(tm, w);
        }
        const float mn = fmaxf(m, tm);
        const float sc = __expf(m - mn);        // 0 on first tile
        den *= sc; acc *= sc; m = mn;
        #pragma unroll
        for (int k = 0; k < 16; ++k) {
            const float p = __expf(ws[k] - m);  // 0 for invalid slots
            den += p;
            acc += p * xv[k];
        }
    }
    float o = (den > 0.0f) ? acc / den : 0.0f;
    o += bias[tid];
    if (FINAL) {
        o = fmaxf(o, 0.0f);
        outd[(size_t)blk * 256 + tid] = o;
    } else {
        outb16[(size_t)blk * 256 + tid] = (__bf16)o;   // t-major, bf16
    }
}

// ---------------------------------------------------------------------------
extern "C" void kernel_launch(void* const* d_in, const int* in_sizes, int n_in,
                              void* d_out, int out_size, void* d_ws, size_t ws_size,
                              hipStream_t stream)
{
    const float* src       = (const float*)d_in[0];
    const float* tgt       = (const float*)d_in[1];
    const float* w_enc_in  = (const float*)d_in[2];
    const float* b_enc_in  = (const float*)d_in[3];
    const float* w_dec_in  = (const float*)d_in[4];
    const float* b_dec_in  = (const float*)d_in[5];
    const float* w_map     = (const float*)d_in[6];
    const float* b_map     = (const float*)d_in[7];
    const float* enc_qkv_w = (const float*)d_in[8];
    const float* enc_qkv_b = (const float*)d_in[9];
    const float* enc_out_w = (const float*)d_in[10];
    const float* enc_out_b = (const float*)d_in[11];
    const float* enc_ff1_w = (const float*)d_in[12];
    const float* enc_ff1_b = (const float*)d_in[13];
    const float* enc_ff2_w = (const float*)d_in[14];
    const float* enc_ff2_b = (const float*)d_in[15];
    const float* enc_ln1_g = (const float*)d_in[16];
    const float* enc_ln1_b = (const float*)d_in[17];
    const float* enc_ln2_g = (const float*)d_in[18];
    const float* enc_ln2_b = (const float*)d_in[19];
    const float* enc_fn_g  = (const float*)d_in[20];
    const float* enc_fn_b  = (const float*)d_in[21];
    const float* dec_sa_qkv_w = (const float*)d_in[22];
    const float* dec_sa_qkv_b = (const float*)d_in[23];
    const float* dec_sa_out_w = (const float*)d_in[24];
    const float* dec_sa_out_b = (const float*)d_in[25];
    const float* dec_ca_qkv_w = (const float*)d_in[26];
    const float* dec_ca_qkv_b = (const float*)d_in[27];
    const float* dec_ca_out_w = (const float*)d_in[28];
    const float* dec_ca_out_b = (const float*)d_in[29];
    const float* dec_ff1_w = (const float*)d_in[30];
    const float* dec_ff1_b = (const float*)d_in[31];
    const float* dec_ff2_w = (const float*)d_in[32];
    const float* dec_ff2_b = (const float*)d_in[33];
    const float* dec_ln1_g = (const float*)d_in[34];
    const float* dec_ln1_b = (const float*)d_in[35];
    const float* dec_ln2_g = (const float*)d_in[36];
    const float* dec_ln2_b = (const float*)d_in[37];
    const float* dec_ln3_g = (const float*)d_in[38];
    const float* dec_ln3_b = (const float*)d_in[39];
    const float* dec_fn_g  = (const float*)d_in[40];
    const float* dec_fn_b  = (const float*)d_in[41];
    const float* g1_wl   = (const float*)d_in[42];
    const float* g1_wr   = (const float*)d_in[43];
    const float* g1_bl   = (const float*)d_in[44];
    const float* g1_br   = (const float*)d_in[45];
    const float* g1_att  = (const float*)d_in[46];
    const float* g1_bias = (const float*)d_in[47];
    const float* g2_wl   = (const float*)d_in[48];
    const float* g2_wr   = (const float*)d_in[49];
    const float* g2_bl   = (const float*)d_in[50];
    const float* g2_br   = (const float*)d_in[51];
    const float* g2_att  = (const float*)d_in[52];
    const float* g2_bias = (const float*)d_in[53];
    const int*   edge_index = (const int*)d_in[54];
    const int* esrc = edge_index;
    const int* edst = edge_index + NEDGE;

    // ---- layout (floats; total ~149 MiB) ----
    float* wsf = (float*)d_ws;
    __bf16* Xb = (__bf16*)wsf;                          // 32768x512 bf16
    __bf16* Yb = (__bf16*)(wsf + 8388608);              // 16384x512 bf16
    float*  Rf = wsf + 12582912;                        // R: 8,388,608 f (32MB)
    float*  Mf = wsf + 20971520;                        // M: 8,388,608 f (32MB)
    float*  Wf = wsf + 29360128;                        // W: 8,388,608 f (32MB)
    float*  F  = wsf + 37748736;                        // 1,048,576 f (4MB)
    int* ipool = (int*)(wsf + 38797312);
    int* deg = ipool;
    int* off = deg + 512;
    int* cur = off + 516;
    int* eid = cur + 512;
    __bf16* Rb16 = (__bf16*)Rf;
    __bf16* Mb16 = (__bf16*)Mf;
    __bf16* Wb   = (__bf16*)Wf;

    auto gemm = [&](const float* A, int lda, const float* B, int ldb, const float* bias,
                    float* Cc, int ldc, int M, int N, int K, int relu) {
        dim3 grid((unsigned)(N / 64), (unsigned)(M / 64));
        gemm_bias<<<grid, 256, 0, stream>>>(A, lda, B, ldb, bias, Cc, ldc, M, N, K, relu);
    };
    auto gemmT = [&](const __bf16* A, int lda, const __bf16* Bt, int ldb,
                     const float* bias, float* Cf, __bf16* Cb, int ldc,
                     int M, int N, int K, int mode) {
        dim3 grid((unsigned)(N / 128), (unsigned)(M / 128));
        gemm_bf16<128><<<grid, 256, 0, stream>>>(A, lda, Bt, ldb, bias, nullptr, Cf, Cb, ldc, M, N, K, mode);
    };
    auto gemmT64 = [&](const __bf16* A, int lda, const __bf16* Bt, int ldb,
                       const float* bias, float* Cf, __bf16* Cb, int ldc,
                       int M, int N, int K, int mode) {
        dim3 grid((unsigned)(N / 64), (unsigned)(M / 128));
        gemm_bf16<64><<<grid, 256, 0, stream>>>(A, lda, Bt, ldb, bias, nullptr, Cf, Cb, ldc, M, N, K, mode);
    };
    auto tw = [&](const float* w, __bf16* o, int K, int N, int L) {
        dim3 g((unsigned)(N / 32), (unsigned)(K / 32), (unsigned)L);
        transpose_w<<<g, 256, 0, stream>>>(w, o, K, N);
    };

    // ---- CSR build ----
    zero_ints<<<8, 256, 0, stream>>>(ipool, 512 + 516 + 512);
    count_deg<<<NEDGE / 256, 256, 0, stream>>>(edst, deg);
    scan512<<<1, 512, 0, stream>>>(deg, off);
    fill_eid<<<NEDGE / 256, 256, 0, stream>>>(edst, off, cur, eid);

    // ---- input permute + fp32 projections + posenc + convert to bf16 ----
    {
        float* src_nm = Wf;
        float* Xtmp = Rf;                       // spans R+M
        permute_in<<<4096, 256, 0, stream>>>(src, src_nm, SLEN, 32, 32768 * 32);
        gemm(src_nm, 32, w_enc_in, 512, b_enc_in, Xtmp, 512, 32768, 512, 32, 0);
        add_posenc<<<(32768 * 512) / 256, 256, 0, stream>>>(Xtmp, SLEN, 32768 * 512);
        conv_bf16<<<16384, 256, 0, stream>>>(Xtmp, Xb, 32768 * 128);
        float* tgt_nm = Wf;
        float* Ytmp = Rf;
        permute_in<<<4096, 256, 0, stream>>>(tgt, tgt_nm, TLEN, 64, 16384 * 64);
        gemm(tgt_nm, 64, w_dec_in, 512, b_dec_in, Ytmp, 512, 16384, 512, 64, 0);
        add_posenc<<<(16384 * 512) / 256, 256, 0, stream>>>(Ytmp, TLEN, 16384 * 512);
        conv_bf16<<<8192, 256, 0, stream>>>(Ytmp, Yb, 16384 * 128);
    }

    // ---- encoder weights -> W (bf16, transposed) ----
    __bf16* WeQkv = Wb + 0;
    __bf16* WeOut = Wb + 3145728;
    __bf16* WeFf1 = Wb + 4194304;
    __bf16* WeFf2 = Wb + 8388608;
    tw(enc_qkv_w, WeQkv, 512, 1536, NLAYER);
    tw(enc_out_w, WeOut, 512, 512, NLAYER);
    tw(enc_ff1_w, WeFf1, 512, 2048, NLAYER);
    tw(enc_ff2_w, WeFf2, 2048, 512, NLAYER);

    // ================= encoder (full batch, 32768 rows) =================
    for (int i = 0; i < NLAYER; ++i) {
        for (int c = 0; c < 4; ++c) {
            gemmT(Xb + (size_t)c * 8192 * 512, 512, WeQkv + (size_t)i * 786432, 512,
                  enc_qkv_b + (size_t)i * 1536, nullptr, Rb16, 1536, 8192, 1536, 512, 3);
            attn_mfma<64, 64, false><<<1024, 64, 0, stream>>>(
                Rb16, 1536, Rb16 + 512, 1536, Rb16 + 1024, 1536,
                Mb16 + (size_t)c * 8192 * 512, 512);
        }
        gemmT(Mb16, 512, WeOut + (size_t)i * 262144, 512, enc_out_b + (size_t)i * 512,
              nullptr, Rb16, 512, 32768, 512, 512, 3);
        ln_bf16<true, false><<<8192, 256, 0, stream>>>(Xb, Rb16,
            enc_ln1_g + (size_t)i * 512, enc_ln1_b + (size_t)i * 512, Xb, nullptr, 32768);
        for (int s = 0; s < 4; ++s) {
            gemmT(Xb + (size_t)s * 8192 * 512, 512, WeFf1 + (size_t)i * 1048576, 512,
                  enc_ff1_b + (size_t)i * 2048, nullptr, Mb16, 2048, 8192, 2048, 512, 2);
            gemmT64(Mb16, 2048, WeFf2 + (size_t)i * 1048576, 2048,
                    enc_ff2_b + (size_t)i * 512, nullptr, Rb16 + (size_t)s * 8192 * 512, 512,
                    8192, 512, 2048, 3);
        }
        ln_bf16<true, false><<<8192, 256, 0, stream>>>(Xb, Rb16,
            enc_ln2_g + (size_t)i * 512, enc_ln2_b + (size_t)i * 512, Xb, nullptr, 32768);
    }
    ln_bf16<false, false><<<8192, 256, 0, stream>>>(Xb, nullptr, enc_fn_g, enc_fn_b,
                                                    Xb, nullptr, 32768);
    // Xb is now MEMb

    // ---- decoder weights -> W ----
    __bf16* WdSaQkv = Wb + 0;
    __bf16* WdSaOut = Wb + 3145728;
    __bf16* WdCaQkv = Wb + 4194304;
    __bf16* WdCaOut = Wb + 7340032;
    __bf16* WdFf1   = Wb + 8388608;
    __bf16* WdFf2   = Wb + 12582912;
    tw(dec_sa_qkv_w, WdSaQkv, 512, 1536, NLAYER);
    tw(dec_sa_out_w, WdSaOut, 512, 512, NLAYER);
    tw(dec_ca_qkv_w, WdCaQkv, 512, 1536, NLAYER);
    tw(dec_ca_out_w, WdCaOut, 512, 512, NLAYER);
    tw(dec_ff1_w,    WdFf1,   512, 2048, NLAYER);
    tw(dec_ff2_w,    WdFf2,   2048, 512, NLAYER);

    // ================= decoder (full batch, 16384 rows) =================
    __bf16* ObD  = Mb16;
    __bf16* QbC  = Mb16;
    __bf16* ObCA = (__bf16*)(Mf + 2097152);
    for (int i = 0; i < NLAYER; ++i) {
        for (int c = 0; c < 2; ++c) {
            gemmT(Yb + (size_t)c * 8192 * 512, 512, WdSaQkv + (size_t)i * 786432, 512,
                  dec_sa_qkv_b + (size_t)i * 1536, nullptr, Rb16, 1536, 8192, 1536, 512, 3);
            attn_mfma<32, 32, true><<<2048, 64, 0, stream>>>(
                Rb16, 1536, Rb16 + 512, 1536, Rb16 + 1024, 1536,
                ObD + (size_t)c * 8192 * 512, 512);
        }
        gemmT64(ObD, 512, WdSaOut + (size_t)i * 262144, 512, dec_sa_out_b + (size_t)i * 512,
                nullptr, Rb16, 512, 16384, 512, 512, 3);
        ln_bf16<true, false><<<4096, 256, 0, stream>>>(Yb, Rb16,
            dec_ln1_g + (size_t)i * 512, dec_ln1_b + (size_t)i * 512, Yb, nullptr, 16384);
        for (int c = 0; c < 2; ++c) {
            gemmT64(Yb + (size_t)c * 8192 * 512, 512, WdCaQkv + (size_t)i * 786432, 512,
                    dec_ca_qkv_b + (size_t)i * 1536, nullptr, QbC, 512, 8192, 512, 512, 3);
            gemmT(Xb + (size_t)c * 16384 * 512, 512, WdCaQkv + (size_t)i * 786432 + 262144, 512,
                  dec_ca_qkv_b + (size_t)i * 1536 + 512, nullptr, Rb16, 1024, 16384, 1024, 512, 3);
            attn_mfma<32, 64, false><<<2048, 64, 0, stream>>>(
                QbC, 512, Rb16, 1024, Rb16 + 512, 1024,
                ObCA + (size_t)c * 8192 * 512, 512);
        }
        gemmT64(ObCA, 512, WdCaOut + (size_t)i * 262144, 512, dec_ca_out_b + (size_t)i * 512,
                nullptr, Rb16, 512, 16384, 512, 512, 3);
        ln_bf16<true, false><<<4096, 256, 0, stream>>>(Yb, Rb16,
            dec_ln2_g + (size_t)i * 512, dec_ln2_b + (size_t)i * 512, Yb, nullptr, 16384);
        for (int s = 0; s < 2; ++s) {
            gemmT(Yb + (size_t)s * 8192 * 512, 512, WdFf1 + (size_t)i * 1048576, 512,
                  dec_ff1_b + (size_t)i * 2048, nullptr, Mb16, 2048, 8192, 2048, 512, 2);
            gemmT64(Mb16, 2048, WdFf2 + (size_t)i * 1048576, 2048,
                    dec_ff2_b + (size_t)i * 512, nullptr, Rb16 + (size_t)s * 8192 * 512, 512,
                    8192, 512, 2048, 3);
        }
        ln_bf16<true, false><<<4096, 256, 0, stream>>>(Yb, Rb16,
            dec_ln3_g + (size_t)i * 512, dec_ln3_b + (size_t)i * 512, Yb, nullptr, 16384);
    }
    // final decoder LN (in place, bf16)
    ln_bf16<false, false><<<4096, 256, 0, stream>>>(Yb, nullptr, dec_fn_g, dec_fn_b,
                                                    Yb, nullptr, 16384);

    // ---- tail weights (W dead after decoder) ----
    __bf16* Wmapt = Wb;                     // 64x512
    __bf16* G1wlT = Wb + 32768;             // 256x64
    __bf16* G1wrT = Wb + 49152;             // 256x64
    __bf16* G2wlT = Wb + 65536;             // 256x256
    __bf16* G2wrT = Wb + 131072;            // 256x256
    __bf16* Ftb   = Wb + 196608;            // 16384x64 (t-major)
    __bf16* Ibb   = Wb + 1245184;           // 16384x256 (t-major, gat1 out)
    tw(w_map, Wmapt, 512, 64, 1);
    tw(g1_wl, G1wlT, 64, 256, 1);
    tw(g1_wr, G1wrT, 64, 256, 1);
    tw(g2_wl, G2wlT, 256, 256, 1);
    tw(g2_wr, G2wrT, 256, 256, 1);

    // map to FEAT=64 (bf16), permute to t-major
    __bf16* Fb16 = (__bf16*)F;
    gemmT64(Yb, 512, Wmapt, 512, b_map, nullptr, Fb16, 64, 16384, 64, 512, 3);
    permute_F<<<4096, 256, 0, stream>>>(Fb16, Ftb);

    // ================= spatial GATv2 (bf16 GEMMs, t-major) =================
    float* G  = Mf;                          // 4,194,304 f
    float* Hb = Mf + 4194304;                // 4,194,304 f
    gemmT64(Ftb, 64, G1wlT, 64, g1_bl, G,  nullptr, 256, 16384, 256, 64, 0);
    gemmT64(Ftb, 64, G1wrT, 64, g1_br, Hb, nullptr, 256, 16384, 256, 64, 0);
    gatv2_kernel<false><<<16384, 256, 0, stream>>>(G, Hb, g1_att, g1_bias, off, eid, esrc,
                                                   Ibb, nullptr);
    gemmT64(Ibb, 256, G2wlT, 256, g2_bl, G,  nullptr, 256, 16384, 256, 256, 0);
    gemmT64(Ibb, 256, G2wrT, 256, g2_br, Hb, nullptr, 256, 16384, 256, 256, 0);
    gatv2_kernel<true><<<16384, 256, 0, stream>>>(G, Hb, g2_att, g2_bias, off, eid, esrc,
                                                  nullptr, (float*)d_out);
}

// Round 14
// 4534.476 us; speedup vs baseline: 1.0671x; 1.0511x over previous
//
#include <hip/hip_runtime.h>
#include <hip/hip_bf16.h>

// Problem constants
#define NHEAD 8
#define SLEN 64
#define TLEN 32
#define NNODE 512
#define NEDGE 16384
#define NLAYER 4

typedef __attribute__((ext_vector_type(8))) __bf16 bf16x8;
typedef __attribute__((ext_vector_type(4))) __bf16 bf16x4;
typedef __attribute__((ext_vector_type(4))) float  f32x4;

// ---------------------------------------------------------------------------
// async global->LDS 16B (wave-uniform LDS base + lane*16 semantics)
// ---------------------------------------------------------------------------
__device__ __forceinline__ void gload16(const void* g, void* l)
{
    __builtin_amdgcn_global_load_lds(
        (const __attribute__((address_space(1))) void*)g,
        (__attribute__((address_space(3))) void*)l, 16, 0, 0);
}

// ---------------------------------------------------------------------------
// bf16 GEMM (m97 structure): A[M][K] bf16, Bt[N][K] bf16 (pre-transposed),
// C = A@B + bias. outMode: 0=f32, 1=f32+relu, 2=bf16+relu, 3=bf16.
// BM=128, BN template {128,64}. M%128==0, N%BN==0, K%64==0.
// ---------------------------------------------------------------------------
template<int BN>
__global__ __launch_bounds__(256) void gemm_bf16(
    const __bf16* __restrict__ A, int lda,
    const __bf16* __restrict__ Bt, int ldb,
    const float* __restrict__ bias,
    float* __restrict__ Cf, __bf16* __restrict__ Cb, int ldc,
    int M, int N, int K, int outMode)
{
    constexpr int FM = (BN == 128) ? 4 : 2;
    __shared__ __bf16 As[128 * 64];
    __shared__ __bf16 Bs[BN * 64];
    const int tid  = threadIdx.x;
    const int wid  = tid >> 6;
    const int lane = tid & 63;
    const int wr = (BN == 128) ? (wid >> 1) : wid;
    const int wc = (BN == 128) ? (wid & 1) : 0;
    const int m0 = blockIdx.y * 128, n0 = blockIdx.x * BN;

    const int srow = wid * 8 + (lane >> 3);
    const int scol = (lane & 7) * 8;
    const int lr = lane & 15;
    const int kg = (lane >> 4) * 8;

    f32x4 acc[FM][4];
    #pragma unroll
    for (int m = 0; m < FM; ++m)
        #pragma unroll
        for (int n = 0; n < 4; ++n)
            acc[m][n] = (f32x4){0.0f, 0.0f, 0.0f, 0.0f};

    for (int k0 = 0; k0 < K; k0 += 64) {
        #pragma unroll
        for (int g = 0; g < 4; ++g) {
            const __bf16* ga = A + (size_t)(m0 + g * 32 + srow) * lda + k0 + scol;
            gload16(ga, &As[(g * 32 + wid * 8) * 64]);
        }
        #pragma unroll
        for (int g = 0; g < BN / 32; ++g) {
            const __bf16* gb = Bt + (size_t)(n0 + g * 32 + srow) * ldb + k0 + scol;
            gload16(gb, &Bs[(g * 32 + wid * 8) * 64]);
        }
        __syncthreads();
        #pragma unroll
        for (int kk = 0; kk < 64; kk += 32) {
            bf16x8 fa[FM], fb[4];
            #pragma unroll
            for (int m = 0; m < FM; ++m)
                fa[m] = *reinterpret_cast<const bf16x8*>(
                    &As[(wr * (16 * FM) + m * 16 + lr) * 64 + kk + kg]);
            #pragma unroll
            for (int n = 0; n < 4; ++n)
                fb[n] = *reinterpret_cast<const bf16x8*>(
                    &Bs[(wc * 64 + n * 16 + lr) * 64 + kk + kg]);
            #pragma unroll
            for (int m = 0; m < FM; ++m)
                #pragma unroll
                for (int n = 0; n < 4; ++n)
                    acc[m][n] = __builtin_amdgcn_mfma_f32_16x16x32_bf16(
                        fa[m], fb[n], acc[m][n], 0, 0, 0);
        }
        __syncthreads();
    }

    const int cr = (lane >> 4) * 4;
    const int cc = lane & 15;
    #pragma unroll
    for (int n = 0; n < 4; ++n) {
        const int gcol = n0 + wc * 64 + n * 16 + cc;
        const float bb = bias[gcol];
        #pragma unroll
        for (int m = 0; m < FM; ++m) {
            #pragma unroll
            for (int j = 0; j < 4; ++j) {
                const int grow = m0 + wr * (16 * FM) + m * 16 + cr + j;
                float v = acc[m][n][j] + bb;
                if (outMode == 1 || outMode == 2) v = fmaxf(v, 0.0f);
                if (outMode >= 2) Cb[(size_t)grow * ldc + gcol] = (__bf16)v;
                else              Cf[(size_t)grow * ldc + gcol] = v;
            }
        }
    }
}

// ---------------------------------------------------------------------------
// fp32 GEMM for input projections, with FUSED posenc + bf16 store.
// posencL > 0: out[m][n] += pe(l = m % posencL, d = n); write bf16 to Cb.
// ---------------------------------------------------------------------------
__global__ __launch_bounds__(256) void gemm_in_pe(
    const float* __restrict__ A, int lda,
    const float* __restrict__ B, int ldb,
    const float* __restrict__ bias,
    __bf16* __restrict__ Cb, int ldc,
    int M, int N, int K, int posencL)
{
    __shared__ float As[16][68];
    __shared__ float Bs[16][68];
    const int tid = threadIdx.x;
    const int tx = tid & 15, ty = tid >> 4;
    const int m0 = blockIdx.y * 64, n0 = blockIdx.x * 64;
    const int liA_m = tid >> 2;
    const int liA_k = (tid & 3) * 4;
    const int liB_n = (tid & 15) * 4;
    const int liB_k = tid >> 4;
    float acc[4][4] = {};
    for (int k0 = 0; k0 < K; k0 += 16) {
        float4 av = *reinterpret_cast<const float4*>(&A[(size_t)(m0 + liA_m) * lda + k0 + liA_k]);
        float4 bv = *reinterpret_cast<const float4*>(&B[(size_t)(k0 + liB_k) * ldb + n0 + liB_n]);
        As[liA_k + 0][liA_m] = av.x;
        As[liA_k + 1][liA_m] = av.y;
        As[liA_k + 2][liA_m] = av.z;
        As[liA_k + 3][liA_m] = av.w;
        *reinterpret_cast<float4*>(&Bs[liB_k][liB_n]) = bv;
        __syncthreads();
        #pragma unroll
        for (int kk = 0; kk < 16; ++kk) {
            float4 a4 = *reinterpret_cast<const float4*>(&As[kk][ty * 4]);
            float4 b4 = *reinterpret_cast<const float4*>(&Bs[kk][tx * 4]);
            float a[4] = {a4.x, a4.y, a4.z, a4.w};
            float b[4] = {b4.x, b4.y, b4.z, b4.w};
            #pragma unroll
            for (int i = 0; i < 4; ++i)
                #pragma unroll
                for (int j = 0; j < 4; ++j)
                    acc[i][j] += a[i] * b[j];
        }
        __syncthreads();
    }
    #pragma unroll
    for (int i = 0; i < 4; ++i) {
        const int m = m0 + ty * 4 + i;
        const int l = m % posencL;
        #pragma unroll
        for (int j = 0; j < 4; ++j) {
            const int n = n0 + tx * 4 + j;
            float v = acc[i][j] + bias[n];
            const int i2 = n & ~1;
            const float freq = __expf(-9.210340371976184f * (float)i2 / 512.0f);
            const float a = (float)l * freq;
            v += (n & 1) ? __cosf(a) : __sinf(a);
            Cb[(size_t)m * ldc + n] = (__bf16)v;
        }
    }
}

// ---------------------------------------------------------------------------
// Tiled transpose + fp32->bf16: in [L][K][N] -> out [L][N][K] (L = gridDim.z)
// ---------------------------------------------------------------------------
__global__ __launch_bounds__(256) void transpose_w(
    const float* __restrict__ in, __bf16* __restrict__ out, int K, int N)
{
    __shared__ __bf16 t[32][33];
    const int l = blockIdx.z;
    in  += (size_t)l * K * N;
    out += (size_t)l * K * N;
    const int k0 = blockIdx.y * 32, n0 = blockIdx.x * 32;
    const int tx = threadIdx.x & 31, ty = threadIdx.x >> 5;
    #pragma unroll
    for (int i = 0; i < 32; i += 8)
        t[ty + i][tx] = (__bf16)in[(size_t)(k0 + ty + i) * N + n0 + tx];
    __syncthreads();
    #pragma unroll
    for (int i = 0; i < 32; i += 8)
        out[(size_t)(n0 + ty + i) * K + k0 + tx] = t[tx][ty + i];
}

// ---------------------------------------------------------------------------
__global__ __launch_bounds__(256) void permute_in(
    const float* __restrict__ in, float* __restrict__ out, int L, int CH, int total)
{
    const int idx = blockIdx.x * 256 + threadIdx.x;
    if (idx >= total) return;
    const int c = idx % CH;
    const int r = idx / CH;       // r = l*512 + n
    const int n = r & 511;
    const int l = r >> 9;
    out[((size_t)n * L + l) * CH + c] = in[idx];
}

// ---------------------------------------------------------------------------
// Permute F bf16 (16384 x 64): node-major row n*32+t -> t-major row t*512+n
// ---------------------------------------------------------------------------
__global__ __launch_bounds__(256) void permute_F(
    const __bf16* __restrict__ in, __bf16* __restrict__ out)
{
    const int idx = blockIdx.x * 256 + threadIdx.x;   // 16384*64 total
    if (idx >= 16384 * 64) return;
    const int c = idx & 63;
    const int r = idx >> 6;
    const int n = r >> 5;
    const int t = r & 31;
    out[((size_t)(t * 512 + n)) * 64 + c] = in[idx];
}

// ---------------------------------------------------------------------------
// MFMA attention: one wave per (node, head). Q/K fragments loaded directly
// from global; only V-transpose + P in LDS. setprio(1) around MFMA (T5).
// ---------------------------------------------------------------------------
template<int LQ, int LK, bool CAUSAL>
__global__ __launch_bounds__(64) void attn_mfma(
    const __bf16* __restrict__ Q, int ldq,
    const __bf16* __restrict__ Kp, int ldk,
    const __bf16* __restrict__ Vp, int ldv,
    __bf16* __restrict__ O, int ldo)
{
    constexpr int QF = LQ / 16, KF = LK / 16;
    constexpr int PSTR = LK + 8;
    __shared__ __bf16 Vt[64 * PSTR];
    __shared__ __bf16 Ps[LQ * PSTR];
    const int n = blockIdx.x >> 3;
    const int h = blockIdx.x & 7;
    const int lane = threadIdx.x;
    const int lr = lane & 15;
    const int g4 = lane >> 4;
    const int kg = g4 * 8;

    if (lane < LK) {
        #pragma unroll
        for (int j = 0; j < 8; ++j) {
            bf16x8 vv = *reinterpret_cast<const bf16x8*>(
                &Vp[(size_t)(n * LK + lane) * ldv + h * 64 + j * 8]);
            #pragma unroll
            for (int e = 0; e < 8; ++e)
                Vt[(j * 8 + e) * PSTR + lane] = vv[e];
        }
    }

    f32x4 s[QF][KF];
    #pragma unroll
    for (int qi = 0; qi < QF; ++qi)
        #pragma unroll
        for (int ki = 0; ki < KF; ++ki)
            s[qi][ki] = (f32x4){0.0f, 0.0f, 0.0f, 0.0f};
    #pragma unroll
    for (int kk = 0; kk < 64; kk += 32) {
        bf16x8 fa[QF], fb[KF];
        #pragma unroll
        for (int qi = 0; qi < QF; ++qi)
            fa[qi] = *reinterpret_cast<const bf16x8*>(
                &Q[(size_t)(n * LQ + qi * 16 + lr) * ldq + h * 64 + kk + kg]);
        #pragma unroll
        for (int ki = 0; ki < KF; ++ki)
            fb[ki] = *reinterpret_cast<const bf16x8*>(
                &Kp[(size_t)(n * LK + ki * 16 + lr) * ldk + h * 64 + kk + kg]);
        __builtin_amdgcn_s_setprio(1);
        #pragma unroll
        for (int qi = 0; qi < QF; ++qi)
            #pragma unroll
            for (int ki = 0; ki < KF; ++ki)
                s[qi][ki] = __builtin_amdgcn_mfma_f32_16x16x32_bf16(fa[qi], fb[ki], s[qi][ki], 0, 0, 0);
        __builtin_amdgcn_s_setprio(0);
    }

    float inv_s[QF][4];
    #pragma unroll
    for (int qi = 0; qi < QF; ++qi) {
        #pragma unroll
        for (int j = 0; j < 4; ++j) {
            const int row = qi * 16 + g4 * 4 + j;
            float mx = -1e30f;
            #pragma unroll
            for (int ki = 0; ki < KF; ++ki) {
                float v = s[qi][ki][j] * 0.125f;
                if (CAUSAL) { const int col = ki * 16 + lr; if (col > row) v = -1e30f; }
                s[qi][ki][j] = v;
                mx = fmaxf(mx, v);
            }
            #pragma unroll
            for (int d = 1; d < 16; d <<= 1) mx = fmaxf(mx, __shfl_xor(mx, d));
            float sum = 0.0f;
            #pragma unroll
            for (int ki = 0; ki < KF; ++ki) {
                const float p = __expf(s[qi][ki][j] - mx);
                s[qi][ki][j] = p;
                sum += p;
            }
            #pragma unroll
            for (int d = 1; d < 16; d <<= 1) sum += __shfl_xor(sum, d);
            inv_s[qi][j] = 1.0f / sum;
            #pragma unroll
            for (int ki = 0; ki < KF; ++ki)
                Ps[row * PSTR + ki * 16 + lr] = (__bf16)s[qi][ki][j];
        }
    }
    __syncthreads();

    f32x4 o[QF][4];
    #pragma unroll
    for (int qi = 0; qi < QF; ++qi)
        #pragma unroll
        for (int di = 0; di < 4; ++di)
            o[qi][di] = (f32x4){0.0f, 0.0f, 0.0f, 0.0f};
    #pragma unroll
    for (int kk = 0; kk < LK; kk += 32) {
        bf16x8 fa[QF], fb[4];
        #pragma unroll
        for (int qi = 0; qi < QF; ++qi)
            fa[qi] = *reinterpret_cast<const bf16x8*>(&Ps[(qi * 16 + lr) * PSTR + kk + kg]);
        #pragma unroll
        for (int di = 0; di < 4; ++di)
            fb[di] = *reinterpret_cast<const bf16x8*>(&Vt[(di * 16 + lr) * PSTR + kk + kg]);
        __builtin_amdgcn_s_setprio(1);
        #pragma unroll
        for (int qi = 0; qi < QF; ++qi)
            #pragma unroll
            for (int di = 0; di < 4; ++di)
                o[qi][di] = __builtin_amdgcn_mfma_f32_16x16x32_bf16(fa[qi], fb[di], o[qi][di], 0, 0, 0);
        __builtin_amdgcn_s_setprio(0);
    }
    #pragma unroll
    for (int qi = 0; qi < QF; ++qi)
        #pragma unroll
        for (int di = 0; di < 4; ++di)
            #pragma unroll
            for (int j = 0; j < 4; ++j) {
                const int row = qi * 16 + g4 * 4 + j;
                O[(size_t)(n * LQ + row) * ldo + h * 64 + di * 16 + lr] =
                    (__bf16)(o[qi][di][j] * inv_s[qi][j]);
            }
}

// ---------------------------------------------------------------------------
// LayerNorm(512) bf16, vectorized (lane owns 8 contiguous channels).
// ---------------------------------------------------------------------------
template<bool HASR, bool F32OUT>
__global__ __launch_bounds__(256) void ln_bf16(
    const __bf16* __restrict__ X, const __bf16* __restrict__ Rb,
    const float* __restrict__ g, const float* __restrict__ b,
    __bf16* __restrict__ outb, float* __restrict__ outf, int ntok)
{
    const int wid = threadIdx.x >> 6, lane = threadIdx.x & 63;
    const int row = blockIdx.x * 4 + wid;
    if (row >= ntok) return;
    const size_t base = (size_t)row * 512;
    const int c0 = lane * 8;
    const bf16x8 xv = *reinterpret_cast<const bf16x8*>(&X[base + c0]);
    float v[8];
    float s = 0.0f;
    if (HASR) {
        const bf16x8 rv = *reinterpret_cast<const bf16x8*>(&Rb[base + c0]);
        #pragma unroll
        for (int j = 0; j < 8; ++j) { v[j] = (float)xv[j] + (float)rv[j]; s += v[j]; }
    } else {
        #pragma unroll
        for (int j = 0; j < 8; ++j) { v[j] = (float)xv[j]; s += v[j]; }
    }
    #pragma unroll
    for (int d = 32; d >= 1; d >>= 1) s += __shfl_xor(s, d, 64);
    const float mean = s * (1.0f / 512.0f);
    float vs = 0.0f;
    #pragma unroll
    for (int j = 0; j < 8; ++j) { const float d = v[j] - mean; vs += d * d; }
    #pragma unroll
    for (int d = 32; d >= 1; d >>= 1) vs += __shfl_xor(vs, d, 64);
    const float rstd = rsqrtf(vs * (1.0f / 512.0f) + 1e-5f);
    const float4 g0 = *reinterpret_cast<const float4*>(&g[c0]);
    const float4 g1 = *reinterpret_cast<const float4*>(&g[c0 + 4]);
    const float4 b0 = *reinterpret_cast<const float4*>(&b[c0]);
    const float4 b1 = *reinterpret_cast<const float4*>(&b[c0 + 4]);
    const float gg[8] = {g0.x, g0.y, g0.z, g0.w, g1.x, g1.y, g1.z, g1.w};
    const float bb[8] = {b0.x, b0.y, b0.z, b0.w, b1.x, b1.y, b1.z, b1.w};
    if (F32OUT) {
        f32x4 o0, o1;
        #pragma unroll
        for (int j = 0; j < 4; ++j) o0[j] = (v[j] - mean) * rstd * gg[j] + bb[j];
        #pragma unroll
        for (int j = 0; j < 4; ++j) o1[j] = (v[4 + j] - mean) * rstd * gg[4 + j] + bb[4 + j];
        *reinterpret_cast<f32x4*>(&outf[base + c0]) = o0;
        *reinterpret_cast<f32x4*>(&outf[base + c0 + 4]) = o1;
    } else {
        bf16x8 w;
        #pragma unroll
        for (int j = 0; j < 8; ++j) w[j] = (__bf16)((v[j] - mean) * rstd * gg[j] + bb[j]);
        *reinterpret_cast<bf16x8*>(&outb[base + c0]) = w;
    }
}

// ---------------------------------------------------------------------------
__global__ void zero_ints(int* __restrict__ p, int n)
{
    const int i = blockIdx.x * 256 + threadIdx.x;
    if (i < n) p[i] = 0;
}

__global__ void count_deg(const int* __restrict__ edst, int* __restrict__ deg)
{
    const int e = blockIdx.x * 256 + threadIdx.x;
    if (e < NEDGE) atomicAdd(&deg[edst[e]], 1);
}

__global__ void scan512(const int* __restrict__ deg, int* __restrict__ off)
{
    __shared__ int s[512];
    const int tid = threadIdx.x;
    s[tid] = deg[tid];
    __syncthreads();
    for (int d = 1; d < 512; d <<= 1) {
        const int t = (tid >= d) ? s[tid - d] : 0;
        __syncthreads();
        s[tid] += t;
        __syncthreads();
    }
    off[tid + 1] = s[tid];
    if (tid == 0) off[0] = 0;
}

__global__ void fill_eid(const int* __restrict__ edst, const int* __restrict__ off,
                         int* __restrict__ cur, int* __restrict__ eid)
{
    const int e = blockIdx.x * 256 + threadIdx.x;
    if (e < NEDGE) {
        const int d = edst[e];
        const int pos = off[d] + atomicAdd(&cur[d], 1);
        eid[pos] = e;
    }
}

// ---------------------------------------------------------------------------
// GATv2 (online softmax, t-major tensors: row = t*512 + node).
// FINAL: fp32 to d_out; else bf16 out (feeds g2 bf16 GEMM).
// ---------------------------------------------------------------------------
template<bool FINAL>
__global__ __launch_bounds__(256) void gatv2_kernel(
    const float* __restrict__ xl, const float* __restrict__ xr,
    const float* __restrict__ att, const float* __restrict__ bias,
    const int* __restrict__ off, const int* __restrict__ eid,
    const int* __restrict__ esrc,
    __bf16* __restrict__ outb16, float* __restrict__ outd)
{
    const int blk = blockIdx.x;       // t*NNODE + i  (== t-major row)
    const int i = blk & (NNODE - 1);
    const int t = blk >> 9;
    const int tid = threadIdx.x;
    const float xrv = xr[(size_t)blk * 256 + tid];
    const float av = att[tid];
    const int e0 = off[i], e1 = off[i + 1];
    float m = -1e30f, den = 0.0f, acc = 0.0f;
    for (int idx = e0; idx < e1; ++idx) {
        const int e = eid[idx];
        const int s = esrc[e];
        const float xlv = xl[((size_t)(t * 512 + s)) * 256 + tid];
        float z = xlv + xrv;
        z = (z > 0.0f) ? z : 0.2f * z;
        float w = z * av;
        #pragma unroll
        for (int d = 16; d >= 1; d >>= 1) w += __shfl_xor(w, d, 32);
        const float mn = fmaxf(m, w);
        const float sc = __expf(m - mn);
        const float p  = __expf(w - mn);
        den = den * sc + p;
        acc = acc * sc + p * xlv;
        m = mn;
    }
    float o = (den > 0.0f) ? acc / den : 0.0f;
    o += bias[tid];
    if (FINAL) {
        o = fmaxf(o, 0.0f);
        outd[(size_t)blk * 256 + tid] = o;
    } else {
        outb16[(size_t)blk * 256 + tid] = (__bf16)o;
    }
}

// ---------------------------------------------------------------------------
extern "C" void kernel_launch(void* const* d_in, const int* in_sizes, int n_in,
                              void* d_out, int out_size, void* d_ws, size_t ws_size,
                              hipStream_t stream)
{
    const float* src       = (const float*)d_in[0];
    const float* tgt       = (const float*)d_in[1];
    const float* w_enc_in  = (const float*)d_in[2];
    const float* b_enc_in  = (const float*)d_in[3];
    const float* w_dec_in  = (const float*)d_in[4];
    const float* b_dec_in  = (const float*)d_in[5];
    const float* w_map     = (const float*)d_in[6];
    const float* b_map     = (const float*)d_in[7];
    const float* enc_qkv_w = (const float*)d_in[8];
    const float* enc_qkv_b = (const float*)d_in[9];
    const float* enc_out_w = (const float*)d_in[10];
    const float* enc_out_b = (const float*)d_in[11];
    const float* enc_ff1_w = (const float*)d_in[12];
    const float* enc_ff1_b = (const float*)d_in[13];
    const float* enc_ff2_w = (const float*)d_in[14];
    const float* enc_ff2_b = (const float*)d_in[15];
    const float* enc_ln1_g = (const float*)d_in[16];
    const float* enc_ln1_b = (const float*)d_in[17];
    const float* enc_ln2_g = (const float*)d_in[18];
    const float* enc_ln2_b = (const float*)d_in[19];
    const float* enc_fn_g  = (const float*)d_in[20];
    const float* enc_fn_b  = (const float*)d_in[21];
    const float* dec_sa_qkv_w = (const float*)d_in[22];
    const float* dec_sa_qkv_b = (const float*)d_in[23];
    const float* dec_sa_out_w = (const float*)d_in[24];
    const float* dec_sa_out_b = (const float*)d_in[25];
    const float* dec_ca_qkv_w = (const float*)d_in[26];
    const float* dec_ca_qkv_b = (const float*)d_in[27];
    const float* dec_ca_out_w = (const float*)d_in[28];
    const float* dec_ca_out_b = (const float*)d_in[29];
    const float* dec_ff1_w = (const float*)d_in[30];
    const float* dec_ff1_b = (const float*)d_in[31];
    const float* dec_ff2_w = (const float*)d_in[32];
    const float* dec_ff2_b = (const float*)d_in[33];
    const float* dec_ln1_g = (const float*)d_in[34];
    const float* dec_ln1_b = (const float*)d_in[35];
    const float* dec_ln2_g = (const float*)d_in[36];
    const float* dec_ln2_b = (const float*)d_in[37];
    const float* dec_ln3_g = (const float*)d_in[38];
    const float* dec_ln3_b = (const float*)d_in[39];
    const float* dec_fn_g  = (const float*)d_in[40];
    const float* dec_fn_b  = (const float*)d_in[41];
    const float* g1_wl   = (const float*)d_in[42];
    const float* g1_wr   = (const float*)d_in[43];
    const float* g1_bl   = (const float*)d_in[44];
    const float* g1_br   = (const float*)d_in[45];
    const float* g1_att  = (const float*)d_in[46];
    const float* g1_bias = (const float*)d_in[47];
    const float* g2_wl   = (const float*)d_in[48];
    const float* g2_wr   = (const float*)d_in[49];
    const float* g2_bl   = (const float*)d_in[50];
    const float* g2_br   = (const float*)d_in[51];
    const float* g2_att  = (const float*)d_in[52];
    const float* g2_bias = (const float*)d_in[53];
    const int*   edge_index = (const int*)d_in[54];
    const int* esrc = edge_index;
    const int* edst = edge_index + NEDGE;

    // ---- layout (floats; total ~149 MiB) ----
    float* wsf = (float*)d_ws;
    __bf16* Xb = (__bf16*)wsf;                          // 32768x512 bf16
    __bf16* Yb = (__bf16*)(wsf + 8388608);              // 16384x512 bf16
    float*  Rf = wsf + 12582912;                        // R: 8,388,608 f (32MB)
    float*  Mf = wsf + 20971520;                        // M: 8,388,608 f (32MB)
    float*  Wf = wsf + 29360128;                        // W: 8,388,608 f (32MB)
    float*  F  = wsf + 37748736;                        // 1,048,576 f (4MB)
    int* ipool = (int*)(wsf + 38797312);
    int* deg = ipool;
    int* off = deg + 512;
    int* cur = off + 516;
    int* eid = cur + 512;
    __bf16* Rb16 = (__bf16*)Rf;
    __bf16* Mb16 = (__bf16*)Mf;
    __bf16* Wb   = (__bf16*)Wf;

    auto gemmT = [&](const __bf16* A, int lda, const __bf16* Bt, int ldb,
                     const float* bias, float* Cf, __bf16* Cb, int ldc,
                     int M, int N, int K, int mode) {
        dim3 grid((unsigned)(N / 128), (unsigned)(M / 128));
        gemm_bf16<128><<<grid, 256, 0, stream>>>(A, lda, Bt, ldb, bias, Cf, Cb, ldc, M, N, K, mode);
    };
    auto gemmT64 = [&](const __bf16* A, int lda, const __bf16* Bt, int ldb,
                       const float* bias, float* Cf, __bf16* Cb, int ldc,
                       int M, int N, int K, int mode) {
        dim3 grid((unsigned)(N / 64), (unsigned)(M / 128));
        gemm_bf16<64><<<grid, 256, 0, stream>>>(A, lda, Bt, ldb, bias, Cf, Cb, ldc, M, N, K, mode);
    };
    auto tw = [&](const float* w, __bf16* o, int K, int N, int L) {
        dim3 g((unsigned)(N / 32), (unsigned)(K / 32), (unsigned)L);
        transpose_w<<<g, 256, 0, stream>>>(w, o, K, N);
    };

    // ---- CSR build ----
    zero_ints<<<8, 256, 0, stream>>>(ipool, 512 + 516 + 512);
    count_deg<<<NEDGE / 256, 256, 0, stream>>>(edst, deg);
    scan512<<<1, 512, 0, stream>>>(deg, off);
    fill_eid<<<NEDGE / 256, 256, 0, stream>>>(edst, off, cur, eid);

    // ---- input permute + fused proj+posenc+bf16 (direct to Xb/Yb) ----
    {
        float* src_nm = Wf;                     // 1,048,576 f scratch
        permute_in<<<4096, 256, 0, stream>>>(src, src_nm, SLEN, 32, 32768 * 32);
        gemm_in_pe<<<dim3(8, 512), 256, 0, stream>>>(src_nm, 32, w_enc_in, 512,
                                                     b_enc_in, Xb, 512, 32768, 512, 32, SLEN);
        float* tgt_nm = Wf;
        permute_in<<<4096, 256, 0, stream>>>(tgt, tgt_nm, TLEN, 64, 16384 * 64);
        gemm_in_pe<<<dim3(8, 256), 256, 0, stream>>>(tgt_nm, 64, w_dec_in, 512,
                                                     b_dec_in, Yb, 512, 16384, 512, 64, TLEN);
    }

    // ---- encoder weights -> W (bf16, transposed) ----
    __bf16* WeQkv = Wb + 0;
    __bf16* WeOut = Wb + 3145728;
    __bf16* WeFf1 = Wb + 4194304;
    __bf16* WeFf2 = Wb + 8388608;
    tw(enc_qkv_w, WeQkv, 512, 1536, NLAYER);
    tw(enc_out_w, WeOut, 512, 512, NLAYER);
    tw(enc_ff1_w, WeFf1, 512, 2048, NLAYER);
    tw(enc_ff2_w, WeFf2, 2048, 512, NLAYER);

    // ================= encoder (full batch, 32768 rows) =================
    for (int i = 0; i < NLAYER; ++i) {
        for (int c = 0; c < 4; ++c) {
            gemmT(Xb + (size_t)c * 8192 * 512, 512, WeQkv + (size_t)i * 786432, 512,
                  enc_qkv_b + (size_t)i * 1536, nullptr, Rb16, 1536, 8192, 1536, 512, 3);
            attn_mfma<64, 64, false><<<1024, 64, 0, stream>>>(
                Rb16, 1536, Rb16 + 512, 1536, Rb16 + 1024, 1536,
                Mb16 + (size_t)c * 8192 * 512, 512);
        }
        gemmT(Mb16, 512, WeOut + (size_t)i * 262144, 512, enc_out_b + (size_t)i * 512,
              nullptr, Rb16, 512, 32768, 512, 512, 3);
        ln_bf16<true, false><<<8192, 256, 0, stream>>>(Xb, Rb16,
            enc_ln1_g + (size_t)i * 512, enc_ln1_b + (size_t)i * 512, Xb, nullptr, 32768);
        for (int s = 0; s < 4; ++s) {
            gemmT(Xb + (size_t)s * 8192 * 512, 512, WeFf1 + (size_t)i * 1048576, 512,
                  enc_ff1_b + (size_t)i * 2048, nullptr, Mb16, 2048, 8192, 2048, 512, 2);
            gemmT64(Mb16, 2048, WeFf2 + (size_t)i * 1048576, 2048,
                    enc_ff2_b + (size_t)i * 512, nullptr, Rb16 + (size_t)s * 8192 * 512, 512,
                    8192, 512, 2048, 3);
        }
        ln_bf16<true, false><<<8192, 256, 0, stream>>>(Xb, Rb16,
            enc_ln2_g + (size_t)i * 512, enc_ln2_b + (size_t)i * 512, Xb, nullptr, 32768);
    }
    ln_bf16<false, false><<<8192, 256, 0, stream>>>(Xb, nullptr, enc_fn_g, enc_fn_b,
                                                    Xb, nullptr, 32768);
    // Xb is now MEMb

    // ---- decoder weights -> W ----
    __bf16* WdSaQkv = Wb + 0;
    __bf16* WdSaOut = Wb + 3145728;
    __bf16* WdCaQkv = Wb + 4194304;
    __bf16* WdCaOut = Wb + 7340032;
    __bf16* WdFf1   = Wb + 8388608;
    __bf16* WdFf2   = Wb + 12582912;
    tw(dec_sa_qkv_w, WdSaQkv, 512, 1536, NLAYER);
    tw(dec_sa_out_w, WdSaOut, 512, 512, NLAYER);
    tw(dec_ca_qkv_w, WdCaQkv, 512, 1536, NLAYER);
    tw(dec_ca_out_w, WdCaOut, 512, 512, NLAYER);
    tw(dec_ff1_w,    WdFf1,   512, 2048, NLAYER);
    tw(dec_ff2_w,    WdFf2,   2048, 512, NLAYER);

    // ================= decoder (full batch, 16384 rows) =================
    __bf16* ObD  = Mb16;                              // 16384x512 bf16 [0,16MB)
    __bf16* QbC  = Mb16;                              // 16384x512 bf16 [0,16MB)
    __bf16* ObCA = (__bf16*)(Mf + 4194304);           // 16384x512 bf16 [16,32MB)
    for (int i = 0; i < NLAYER; ++i) {
        for (int c = 0; c < 2; ++c) {
            gemmT(Yb + (size_t)c * 8192 * 512, 512, WdSaQkv + (size_t)i * 786432, 512,
                  dec_sa_qkv_b + (size_t)i * 1536, nullptr, Rb16, 1536, 8192, 1536, 512, 3);
            attn_mfma<32, 32, true><<<2048, 64, 0, stream>>>(
                Rb16, 1536, Rb16 + 512, 1536, Rb16 + 1024, 1536,
                ObD + (size_t)c * 8192 * 512, 512);
        }
        gemmT64(ObD, 512, WdSaOut + (size_t)i * 262144, 512, dec_sa_out_b + (size_t)i * 512,
                nullptr, Rb16, 512, 16384, 512, 512, 3);
        ln_bf16<true, false><<<4096, 256, 0, stream>>>(Yb, Rb16,
            dec_ln1_g + (size_t)i * 512, dec_ln1_b + (size_t)i * 512, Yb, nullptr, 16384);
        // cross-attention: single full-batch Q, chunked KV over enc rows
        gemmT64(Yb, 512, WdCaQkv + (size_t)i * 786432, 512,
                dec_ca_qkv_b + (size_t)i * 1536, nullptr, QbC, 512, 16384, 512, 512, 3);
        for (int c = 0; c < 2; ++c) {
            gemmT(Xb + (size_t)c * 16384 * 512, 512, WdCaQkv + (size_t)i * 786432 + 262144, 512,
                  dec_ca_qkv_b + (size_t)i * 1536 + 512, nullptr, Rb16, 1024, 16384, 1024, 512, 3);
            attn_mfma<32, 64, false><<<2048, 64, 0, stream>>>(
                QbC + (size_t)c * 8192 * 512, 512, Rb16, 1024, Rb16 + 512, 1024,
                ObCA + (size_t)c * 8192 * 512, 512);
        }
        gemmT64(ObCA, 512, WdCaOut + (size_t)i * 262144, 512, dec_ca_out_b + (size_t)i * 512,
                nullptr, Rb16, 512, 16384, 512, 512, 3);
        ln_bf16<true, false><<<4096, 256, 0, stream>>>(Yb, Rb16,
            dec_ln2_g + (size_t)i * 512, dec_ln2_b + (size_t)i * 512, Yb, nullptr, 16384);
        for (int s = 0; s < 2; ++s) {
            gemmT(Yb + (size_t)s * 8192 * 512, 512, WdFf1 + (size_t)i * 1048576, 512,
                  dec_ff1_b + (size_t)i * 2048, nullptr, Mb16, 2048, 8192, 2048, 512, 2);
            gemmT64(Mb16, 2048, WdFf2 + (size_t)i * 1048576, 2048,
                    dec_ff2_b + (size_t)i * 512, nullptr, Rb16 + (size_t)s * 8192 * 512, 512,
                    8192, 512, 2048, 3);
        }
        ln_bf16<true, false><<<4096, 256, 0, stream>>>(Yb, Rb16,
            dec_ln3_g + (size_t)i * 512, dec_ln3_b + (size_t)i * 512, Yb, nullptr, 16384);
    }
    ln_bf16<false, false><<<4096, 256, 0, stream>>>(Yb, nullptr, dec_fn_g, dec_fn_b,
                                                    Yb, nullptr, 16384);

    // ---- tail weights (W dead after decoder) ----
    __bf16* Wmapt = Wb;                     // 64x512
    __bf16* G1wlT = Wb + 32768;             // 256x64
    __bf16* G1wrT = Wb + 49152;             // 256x64
    __bf16* G2wlT = Wb + 65536;             // 256x256
    __bf16* G2wrT = Wb + 131072;            // 256x256
    __bf16* Ftb   = Wb + 196608;            // 16384x64 (t-major)
    __bf16* Ibb   = Wb + 1245184;           // 16384x256 (t-major, gat1 out)
    tw(w_map, Wmapt, 512, 64, 1);
    tw(g1_wl, G1wlT, 64, 256, 1);
    tw(g1_wr, G1wrT, 64, 256, 1);
    tw(g2_wl, G2wlT, 256, 256, 1);
    tw(g2_wr, G2wrT, 256, 256, 1);

    // map to FEAT=64 (bf16), permute to t-major
    __bf16* Fb16 = (__bf16*)F;
    gemmT64(Yb, 512, Wmapt, 512, b_map, nullptr, Fb16, 64, 16384, 64, 512, 3);
    permute_F<<<4096, 256, 0, stream>>>(Fb16, Ftb);

    // ================= spatial GATv2 (bf16 GEMMs, t-major) =================
    float* G  = Mf;                          // 4,194,304 f
    float* Hb = Mf + 4194304;                // 4,194,304 f
    gemmT64(Ftb, 64, G1wlT, 64, g1_bl, G,  nullptr, 256, 16384, 256, 64, 0);
    gemmT64(Ftb, 64, G1wrT, 64, g1_br, Hb, nullptr, 256, 16384, 256, 64, 0);
    gatv2_kernel<false><<<16384, 256, 0, stream>>>(G, Hb, g1_att, g1_bias, off, eid, esrc,
                                                   Ibb, nullptr);
    gemmT64(Ibb, 256, G2wlT, 256, g2_bl, G,  nullptr, 256, 16384, 256, 256, 0);
    gemmT64(Ibb, 256, G2wrT, 256, g2_br, Hb, nullptr, 256, 16384, 256, 256, 0);
    gatv2_kernel<true><<<16384, 256, 0, stream>>>(G, Hb, g2_att, g2_bias, off, eid, esrc,
                                                  nullptr, (float*)d_out);
}